// Round 8
// baseline (2446.333 us; speedup 1.0000x reference)
//
#include <hip/hip_runtime.h>

typedef unsigned short u16;
typedef unsigned int   u32;

#define B_     4
#define L_     392
#define T_     1568   // B_*L_
#define DM     384
#define DI     768
#define DS     16
#define DTR    24
#define DEPTH_ 24
#define NPATCH 196
#define NC     28    // scan chunks
#define CL     14    // chunk length (NC*CL == L_)

// xproj_conv: K-split 8 -> 96 d's per block; LDS row pitch 104 (208B = 13*16B)
#define XKC    96
#define XPAD   104
// gemm_out: K-split 2 -> 384 d's per block; LDS row pitch 392 u16 (784B = 49*16B)
#define OKC    384
#define OPAD   392

typedef __bf16 bf16x8 __attribute__((ext_vector_type(8)));
typedef float  f32x4  __attribute__((ext_vector_type(4)));
typedef u16    u16x4  __attribute__((ext_vector_type(4)));
typedef u16    u16x8  __attribute__((ext_vector_type(8)));

__device__ __forceinline__ u16 f2bf(float f) {
  union { float f; u32 u; } v; v.f = f;
  return (u16)((v.u + 0x7fffu + ((v.u >> 16) & 1u)) >> 16);  // RNE
}
__device__ __forceinline__ float bf2f(u16 h) {
  union { u32 u; float f; } v; v.u = (u32)h << 16; return v.f;
}

// ---------------- one-shot repack: fp32 -> bf16 fragment layout, DST-coalesced ----------------
// Fragment layout per matrix [R rows][K]: dst[ly][p=row/16][kb=k/8][r=row%16][e=k%8].
// Thread i owns dst u16 range [i*8, i*8+8) -> one 16B coalesced store; source side is
// two float4 loads (lanes l and l+16 share a 64B line).
#define RQ0 36864      // patchW: R=384  KB=96  L=1
#define RQ1 1769472    // inW:    R=1536 KB=48  L=24
#define RQ2 147456     // xpW:    Rp=64  KB=96  L=24 (rows 56..63 zero)
#define RQ3 884736     // outW:   R=384  KB=96  L=24
#define RQ4 43904      // dbl zero fill, float4 units
#define RQ_TOT (RQ0+RQ1+RQ2+RQ3+RQ4)

__global__ __launch_bounds__(256) void repack_kernel(
    const float* __restrict__ patchW, u16* __restrict__ pwB,
    const float* __restrict__ inW,    u16* __restrict__ inWb,
    const float* __restrict__ xpW,    u16* __restrict__ xpWb,
    const float* __restrict__ outW,   u16* __restrict__ outWb,
    float* __restrict__ dblz) {
  int i = blockIdx.x * 256 + threadIdx.x;
  const float* sp = nullptr; u16* dp = nullptr;
  if (i < RQ0) {                      // patchW
    int r = i & 15, kb = (i >> 4) % 96, p = i / (16 * 96);
    sp = patchW + (size_t)(p * 16 + r) * 768 + kb * 8;
    dp = pwB + (size_t)i * 8;
  } else { i -= RQ0;
  if (i < RQ1) {                      // inW
    const int per = 1536 * 48;
    int ly = i / per, rem = i - ly * per;
    int r = rem & 15, kb = (rem >> 4) % 48, p = rem / (16 * 48);
    sp = inW + (size_t)ly * 1536 * 384 + (size_t)(p * 16 + r) * 384 + kb * 8;
    dp = inWb + (size_t)i * 8;
  } else { i -= RQ1;
  if (i < RQ2) {                      // xpW (padded rows -> zeros)
    const int per = 64 * 96;
    int ly = i / per, rem = i - ly * per;
    int r = rem & 15, kb = (rem >> 4) % 96, p = rem / (16 * 96);
    int row = p * 16 + r;
    dp = xpWb + (size_t)i * 8;
    if (row < 56) {
      sp = xpW + (size_t)ly * 56 * 768 + (size_t)row * 768 + kb * 8;
    } else {
      u16x8 zz = {0,0,0,0,0,0,0,0};
      *(u16x8*)dp = zz;
      return;
    }
  } else { i -= RQ2;
  if (i < RQ3) {                      // outW
    const int per = 384 * 96;
    int ly = i / per, rem = i - ly * per;
    int r = rem & 15, kb = (rem >> 4) % 96, p = rem / (16 * 96);
    sp = outW + (size_t)ly * 384 * 768 + (size_t)(p * 16 + r) * 768 + kb * 8;
    dp = outWb + (size_t)i * 8;
  } else { i -= RQ3;
  if (i < RQ4) {                      // zero both dbl halves
    ((float4*)dblz)[i] = make_float4(0.f, 0.f, 0.f, 0.f);
  }
  return; } } } }
  float4 a = *(const float4*)sp;
  float4 b = *(const float4*)(sp + 4);
  u16x8 r8;
  r8[0] = f2bf(a.x); r8[1] = f2bf(a.y); r8[2] = f2bf(a.z); r8[3] = f2bf(a.w);
  r8[4] = f2bf(b.x); r8[5] = f2bf(b.y); r8[6] = f2bf(b.z); r8[7] = f2bf(b.w);
  *(u16x8*)dp = r8;
}

// ---------------- im2col for patch embed, emitting A-side fragment layout ----------------
__global__ __launch_bounds__(256) void imcol_kernel(const float* __restrict__ z,
                                                    const float* __restrict__ x,
                                                    u16* __restrict__ out) {
  int idx = blockIdx.x * 256 + threadIdx.x;        // t*768 + k
  int t = idx / 768, k = idx - t * 768;
  int b = t / L_, l = t - b * L_;
  const float* img = (l < NPATCH) ? z : x;
  int p  = (l < NPATCH) ? l : l - NPATCH;
  int py = p / 14, px = p - py * 14;
  int ic = k >> 8, rem = k & 255, i = rem >> 4, j = rem & 15;
  float v = img[((size_t)b * 3 + ic) * 50176 + (size_t)(py * 16 + i) * 224 + (px * 16 + j)];
  size_t o = ((size_t)(t >> 4) * 96 + (k >> 3)) * 128 + (size_t)(t & 15) * 8 + (k & 7);
  out[o] = f2bf(v);
}

// ---------------- patch embed GEMM: both operands fragment-native, no LDS ----------------
// h[t][n] = imcolF(t,:) . pwB(n,:) + patch_b[n] + pos[1 + (t%L)%NPATCH][n]. grid (25, 6).
__global__ __launch_bounds__(256) void gemm_patch(const u16* __restrict__ Af,
                                                  const u16* __restrict__ Wf,
                                                  const float* __restrict__ pb,
                                                  const float* __restrict__ pos,
                                                  float* __restrict__ h) {
  int wave = threadIdx.x >> 6, lane = threadIdx.x & 63;
  int r = lane & 15, quad = lane >> 4;
  int t0 = blockIdx.x * 64;
  int p  = blockIdx.y * 4 + wave;
  const u16* wp  = Wf + ((size_t)p * 96 + quad) * 128 + (size_t)r * 8;
  const u16* ap0 = Af + ((size_t)(t0 >> 4) * 96 + quad) * 128 + (size_t)r * 8;

  f32x4 acc[4] = {f32x4{0,0,0,0}, f32x4{0,0,0,0}, f32x4{0,0,0,0}, f32x4{0,0,0,0}};
#pragma unroll
  for (int k0 = 0; k0 < 768; k0 += 32) {
    bf16x8 bfrag = *(const bf16x8*)(wp + (size_t)(k0 >> 3) * 128);
#pragma unroll
    for (int mi = 0; mi < 4; ++mi) {
      bf16x8 afrag = *(const bf16x8*)(ap0 + ((size_t)mi * 96 + (k0 >> 3)) * 128);
      acc[mi] = __builtin_amdgcn_mfma_f32_16x16x32_bf16(afrag, bfrag, acc[mi], 0, 0, 0);
    }
  }
  int ccol = blockIdx.y * 64 + wave * 16 + r;
  float pbv = pb[ccol];
#pragma unroll
  for (int mi = 0; mi < 4; ++mi) {
#pragma unroll
    for (int rr = 0; rr < 4; ++rr) {
      int crow = t0 + mi * 16 + quad * 4 + rr;
      if (crow < T_) {
        int pp = (crow % L_) % NPATCH;
        h[(size_t)crow * DM + ccol] = acc[mi][rr] + pbv + pos[(size_t)(1 + pp) * DM + ccol];
      }
    }
  }
}

// ---------------- fused LayerNorm + in_proj GEMM (coalesced, frag weights) ----------------
__global__ __launch_bounds__(256) void gemm_ln(const float* __restrict__ h,
                                               const float* __restrict__ lw,
                                               const float* __restrict__ lb,
                                               const u16* __restrict__ W3,
                                               u16* __restrict__ xzt) {
  __shared__ u16 atile[64][392];
  int tid = threadIdx.x;
  int w = tid >> 6, l = tid & 63;
  int tok0 = blockIdx.y * 64;

  const int cA = 4 * l;
  const int cB = 256 + 4 * l;
  float4 wA = *(const float4*)(lw + cA);
  float4 bA = *(const float4*)(lb + cA);
  float4 wB = make_float4(0.f, 0.f, 0.f, 0.f), bB = wB;
  if (l < 32) { wB = *(const float4*)(lw + cB); bB = *(const float4*)(lb + cB); }

#pragma unroll 4
  for (int tt = 0; tt < 16; ++tt) {
    int t = w * 16 + tt;
    int tg = tok0 + t; if (tg > T_ - 1) tg = T_ - 1;
    const float* hrow = h + (size_t)tg * DM;
    float4 a = *(const float4*)(hrow + cA);
    float4 b2 = make_float4(0.f, 0.f, 0.f, 0.f);
    if (l < 32) b2 = *(const float4*)(hrow + cB);
    float s  = a.x + a.y + a.z + a.w + b2.x + b2.y + b2.z + b2.w;
    float s2 = a.x * a.x + a.y * a.y + a.z * a.z + a.w * a.w
             + b2.x * b2.x + b2.y * b2.y + b2.z * b2.z + b2.w * b2.w;
#pragma unroll
    for (int o = 32; o; o >>= 1) { s += __shfl_xor(s, o); s2 += __shfl_xor(s2, o); }
    float mu = s * (1.f / DM);
    float rs = rsqrtf(s2 * (1.f / DM) - mu * mu + 1e-5f);
    u16x4 r4;
    r4.x = f2bf((a.x - mu) * rs * wA.x + bA.x);
    r4.y = f2bf((a.y - mu) * rs * wA.y + bA.y);
    r4.z = f2bf((a.z - mu) * rs * wA.z + bA.z);
    r4.w = f2bf((a.w - mu) * rs * wA.w + bA.w);
    *(u16x4*)&atile[t][cA] = r4;
    if (l < 32) {
      u16x4 r4b;
      r4b.x = f2bf((b2.x - mu) * rs * wB.x + bB.x);
      r4b.y = f2bf((b2.y - mu) * rs * wB.y + bB.y);
      r4b.z = f2bf((b2.z - mu) * rs * wB.z + bB.z);
      r4b.w = f2bf((b2.w - mu) * rs * wB.w + bB.w);
      *(u16x4*)&atile[t][cB] = r4b;
    }
  }
  __syncthreads();

  int r = l & 15, u = l >> 4;
  int pbase = blockIdx.x * 4;
  const u16* wp = W3 + ((size_t)pbase * 48 + (size_t)u) * 128 + (size_t)r * 8;
  const u16* lp = &atile[w * 16 + r][u * 8];

  f32x4 acc[4] = {f32x4{0,0,0,0}, f32x4{0,0,0,0}, f32x4{0,0,0,0}, f32x4{0,0,0,0}};
#pragma unroll
  for (int k0 = 0; k0 < DM; k0 += 32) {
    bf16x8 bfrag = *(const bf16x8*)(lp + k0);
#pragma unroll
    for (int mi = 0; mi < 4; ++mi) {
      bf16x8 afrag = *(const bf16x8*)(wp + ((size_t)mi * 48 + (k0 >> 3)) * 128);
      acc[mi] = __builtin_amdgcn_mfma_f32_16x16x32_bf16(afrag, bfrag, acc[mi], 0, 0, 0);
    }
  }
  int ccol = tok0 + w * 16 + r;
  if (ccol < T_) {
#pragma unroll
    for (int mi = 0; mi < 4; ++mi) {
#pragma unroll
      for (int rr2 = 0; rr2 < 4; ++rr2) {
        int crow = pbase * 16 + mi * 16 + u * 4 + rr2;
        xzt[(size_t)crow * T_ + ccol] = f2bf(acc[mi][rr2]);
      }
    }
  }
}

// ---------------- fused conv3+SiLU + x_proj GEMM (frag weights) ----------------
// dbl[T,56] += conv(xzt)·xpW^T over d-slice. grid (25, 1, 8), atomic epilogue.
__global__ __launch_bounds__(256) void xproj_conv(const u16* __restrict__ xzt,
                                                  const float* __restrict__ cw,
                                                  const float* __restrict__ cb,
                                                  const u16* __restrict__ Wx3,
                                                  float* __restrict__ dbl) {
  __shared__ u16 tile[64][XPAD];
  int t0 = blockIdx.x * 64;
  int kbeg = blockIdx.z * XKC;
  int tid = threadIdx.x;
  int tl = tid & 63, rq = tid >> 6;
  int t = t0 + tl;
  int tc = (t < T_) ? t : T_ - 1;
  int l = tc % L_;
  for (int kkb = rq * 2; kkb < XKC; kkb += 8) {
    u32 pack = 0;
#pragma unroll
    for (int ss = 0; ss < 2; ++ss) {
      int d = kbeg + kkb + ss;
      const u16* row = xzt + (size_t)d * T_ + tc;
      float acc = cb[d] + cw[d * 3 + 2] * bf2f(row[0]);
      if (l >= 1) acc += cw[d * 3 + 1] * bf2f(row[-1]);
      if (l >= 2) acc += cw[d * 3 + 0] * bf2f(row[-2]);
      float v = acc / (1.f + __expf(-acc));
      pack |= (u32)f2bf(v) << (16 * ss);
    }
    *(u32*)&tile[tl][kkb] = pack;
  }
  __syncthreads();

  int wave = tid >> 6, lane = tid & 63;
  int r = lane & 15, quad = lane >> 4;
  int wcol = wave * 16 + r;
  const u16* wp = Wx3 + ((size_t)wave * 96 + (kbeg >> 3) + quad) * 128 + (size_t)r * 8;

  f32x4 acc4[4] = {f32x4{0,0,0,0}, f32x4{0,0,0,0}, f32x4{0,0,0,0}, f32x4{0,0,0,0}};
#pragma unroll
  for (int k0 = 0; k0 < XKC; k0 += 32) {
    bf16x8 bfrag = *(const bf16x8*)(wp + (size_t)(k0 >> 3) * 128);
#pragma unroll
    for (int mi = 0; mi < 4; ++mi) {
      bf16x8 afrag = *(const bf16x8*)&tile[mi * 16 + r][k0 + quad * 8];
      acc4[mi] = __builtin_amdgcn_mfma_f32_16x16x32_bf16(afrag, bfrag, acc4[mi], 0, 0, 0);
    }
  }
  if (wcol < 56) {
#pragma unroll
    for (int mi = 0; mi < 4; ++mi) {
#pragma unroll
      for (int rr = 0; rr < 4; ++rr) {
        int crow = t0 + mi * 16 + quad * 4 + rr;
        if (crow < T_) atomicAdd(&dbl[(size_t)crow * 56 + wcol], acc4[mi][rr]);
      }
    }
  }
}

// ---------------- fused transpose + out_proj GEMM (frag weights, K-split 2) ----------------
// h[T,384] += y^T·outW^T over d-slice. grid (25, 6, 2), atomic epilogue.
__global__ __launch_bounds__(256) void gemm_out(const u16* __restrict__ yt,
                                                const u16* __restrict__ Wo3,
                                                float* __restrict__ h) {
  __shared__ u16 tile[64][OPAD];
  int t0 = blockIdx.x * 64;
  int kbeg = blockIdx.z * OKC;
  int tid = threadIdx.x;
  {
    int tl2 = tid & 31, rq = tid >> 5;   // 8 rows per pass
    for (int kk = rq; kk < OKC; kk += 8) {
      int d = kbeg + kk;
      u32 v = *(const u32*)(yt + (size_t)d * T_ + t0 + tl2 * 2);
      tile[tl2 * 2][kk]     = (u16)v;
      tile[tl2 * 2 + 1][kk] = (u16)(v >> 16);
    }
  }
  __syncthreads();

  int wave = tid >> 6, lane = tid & 63;
  int r = lane & 15, quad = lane >> 4;
  int p = blockIdx.y * 4 + wave;
  const u16* wp = Wo3 + ((size_t)p * 96 + (kbeg >> 3) + quad) * 128 + (size_t)r * 8;

  f32x4 acc[4] = {f32x4{0,0,0,0}, f32x4{0,0,0,0}, f32x4{0,0,0,0}, f32x4{0,0,0,0}};
#pragma unroll
  for (int k0 = 0; k0 < OKC; k0 += 32) {
    bf16x8 bfrag = *(const bf16x8*)(wp + (size_t)(k0 >> 3) * 128);
#pragma unroll
    for (int mi = 0; mi < 4; ++mi) {
      bf16x8 afrag = *(const bf16x8*)&tile[mi * 16 + r][k0 + quad * 8];
      acc[mi] = __builtin_amdgcn_mfma_f32_16x16x32_bf16(afrag, bfrag, acc[mi], 0, 0, 0);
    }
  }
  int ccol = blockIdx.y * 64 + wave * 16 + r;
#pragma unroll
  for (int mi = 0; mi < 4; ++mi) {
#pragma unroll
    for (int rr = 0; rr < 4; ++rr) {
      int crow = t0 + mi * 16 + quad * 4 + rr;
      if (crow < T_) atomicAdd(&h[(size_t)crow * DM + ccol], acc[mi][rr]);
    }
  }
}

// ---------------- LayerNorm over DM per token (final only) ----------------
__global__ __launch_bounds__(384) void ln_kernel(const float* __restrict__ x,
                                                 const float* __restrict__ w,
                                                 const float* __restrict__ b,
                                                 float* __restrict__ out_f) {
  int t = blockIdx.x;
  int i = threadIdx.x;
  float v = x[(size_t)t * DM + i];
  float s = v, s2 = v * v;
#pragma unroll
  for (int o = 32; o; o >>= 1) { s += __shfl_xor(s, o); s2 += __shfl_xor(s2, o); }
  __shared__ float ls[6], ls2[6];
  int wv = i >> 6;
  if ((i & 63) == 0) { ls[wv] = s; ls2[wv] = s2; }
  __syncthreads();
  float ts = 0.f, ts2 = 0.f;
#pragma unroll
  for (int j = 0; j < 6; ++j) { ts += ls[j]; ts2 += ls2[j]; }
  float mu  = ts * (1.f / DM);
  float var = ts2 * (1.f / DM) - mu * mu;
  float rs  = rsqrtf(var + 1e-5f);
  out_f[(size_t)t * DM + i] = (v - mu) * rs * w[i] + b[i];
}

// ---------------- chunked selective scan v9: NC=28, CL=14, 448 threads, 1 d/block ----------------
// dt-dot inputs staged through LDS: one fully-coalesced linear float4 sweep of the
// block's contiguous dbl b-slice (keeps cols 0..23 as packed bf16 pairs, pitch-13 u32
// -> conflict-free). Replaces the 224B-stride 64-line/instruction gather. The stage
// buffer unions with hC (dead until phase 4) -> LDS footprint unchanged.
__global__ __launch_bounds__(448) void scan_kernel(const u16* __restrict__ xzt,
                                                   const float* __restrict__ dbl,
                                                   const float* __restrict__ cw,
                                                   const float* __restrict__ cb,
                                                   const float* __restrict__ dtW,
                                                   const float* __restrict__ dtB,
                                                   const float* __restrict__ Alog,
                                                   const float* __restrict__ Dp,
                                                   u16* __restrict__ yt,
                                                   float* __restrict__ dblz) {
  int bd = blockIdx.x;          // b*DI + d
  int d  = bd % DI;
  int b  = bd / DI;
  int tid = threadIdx.x;
  int n = tid & 15, c = tid >> 4;   // c in [0,28)

  __shared__ float dtsh[L_];
  __shared__ float zsh[L_];
  __shared__ float xcsh[L_];
  __shared__ float Psh[NC][DS], Ssh[NC][DS], Hsh[NC][DS];
  __shared__ u32 smem[L_ * 17];   // union: stage [392][13] u32 (phase 1) / hC [392][17] f32 (phase 4+)
  float* hC = (float*)smem;       // hC[l][k] = hC[l*17+k], pad 17 -> conflict-free column access

  // zero slice of next dbl buffer (29 floats per block)
  {
    int i0 = blockIdx.x * 29 + tid;
    if (tid < 29 && i0 < T_ * 56) dblz[i0] = 0.f;
  }

  // stage dt-cols (0..23) of the contiguous b-slice as bf16 pairs, fully coalesced
  {
    const float4* src = (const float4*)(dbl + (size_t)b * L_ * 56);
    for (int idx = tid; idx < L_ * 56 / 4; idx += 448) {
      int e = idx * 4;
      int t = e / 56, cc = e - t * 56;    // cc in {0,4,...,52}
      float4 v = src[idx];
      if (cc < 24) {
        u32 lo = (u32)f2bf(v.x) | ((u32)f2bf(v.y) << 16);
        u32 hi = (u32)f2bf(v.z) | ((u32)f2bf(v.w) << 16);
        smem[t * 13 + (cc >> 1)]     = lo;
        smem[t * 13 + (cc >> 1) + 1] = hi;
      }
    }
  }
  __syncthreads();

  // cooperative: dt projection (from LDS) + softplus, conv row (recompute), silu(z)
  const float* wr = dtW + (size_t)d * DTR;   // block-uniform -> scalar loads
  float bias = dtB[d];
  float w0 = cw[d * 3 + 0], w1 = cw[d * 3 + 1], w2 = cw[d * 3 + 2], cbd = cb[d];
  const u16* xrow = xzt + (size_t)d * T_ + b * L_;
  const u16* zrow = xzt + (size_t)(DI + d) * T_ + b * L_;
  if (tid < L_) {
    int l = tid;
    float s = bias;
#pragma unroll
    for (int p = 0; p < 12; ++p) {
      u32 wv = smem[l * 13 + p];
      s += bf2f((u16)wv) * wr[2 * p] + bf2f((u16)(wv >> 16)) * wr[2 * p + 1];
    }
    dtsh[l] = (s > 20.f) ? s : log1pf(__expf(s));
    float zv = bf2f(zrow[l]);
    zsh[l] = zv / (1.f + __expf(-zv));
    float a = cbd + w2 * bf2f(xrow[l]);
    if (l >= 1) a += w1 * bf2f(xrow[l - 1]);
    if (l >= 2) a += w0 * bf2f(xrow[l - 2]);
    xcsh[l] = a / (1.f + __expf(-a));
  }
  float A  = -__expf(Alog[(size_t)d * DS + n]);
  float Dd = Dp[d];
  __syncthreads();

  int tb = b * L_ + c * CL;
  const float* Bp = dbl + (size_t)tb * 56 + DTR + n;
  const float* Cp = Bp + DS;

  float dA[CL], dBu[CL];
  {
    float P = 1.f, S = 0.f;
#pragma unroll
    for (int l = 0; l < CL; ++l) {
      float dtv = dtsh[c * CL + l];
      float xcv = xcsh[c * CL + l];
      float Bv  = Bp[l * 56];
      float e = __expf(dtv * A);
      float u = dtv * xcv * Bv;
      dA[l] = e; dBu[l] = u;
      P *= e;
      S = e * S + u;
    }
    Psh[c][n] = P; Ssh[c][n] = S;
  }
  __syncthreads();
  if (tid < DS) {   // thread n: serial combine over 28 chunks
    float hh = 0.f;
#pragma unroll
    for (int cc = 0; cc < NC; ++cc) {
      Hsh[cc][tid] = hh;
      hh = Psh[cc][tid] * hh + Ssh[cc][tid];
    }
  }
  __syncthreads();
  {
    float hh = Hsh[c][n];
#pragma unroll
    for (int l = 0; l < CL; ++l) {
      hh = dA[l] * hh + dBu[l];
      hC[(c * CL + l) * 17 + n] = hh * Cp[l * 56];
    }
  }
  __syncthreads();
  if (tid < L_) {   // thread l: reduce over n, gate, coalesced y store
    int l = tid;
    float p = 0.f;
#pragma unroll
    for (int k = 0; k < DS; ++k) p += hC[l * 17 + k];
    yt[(size_t)d * T_ + b * L_ + l] = f2bf((p + Dd * xcsh[l]) * zsh[l]);
  }
}

extern "C" void kernel_launch(void* const* d_in, const int* in_sizes, int n_in,
                              void* d_out, int out_size, void* d_ws, size_t ws_size,
                              hipStream_t stream) {
  const float* z      = (const float*)d_in[0];
  const float* x      = (const float*)d_in[1];
  const float* patchW = (const float*)d_in[2];
  const float* patchB = (const float*)d_in[3];
  const float* pos    = (const float*)d_in[4];
  const float* normW  = (const float*)d_in[5];
  const float* normB  = (const float*)d_in[6];
  const float* inW    = (const float*)d_in[7];
  const float* convW  = (const float*)d_in[8];
  const float* convB  = (const float*)d_in[9];
  const float* xprojW = (const float*)d_in[10];
  const float* dtW    = (const float*)d_in[11];
  const float* dtB    = (const float*)d_in[12];
  const float* Alog   = (const float*)d_in[13];
  const float* Dpar   = (const float*)d_in[14];
  const float* outW   = (const float*)d_in[15];
  const float* fnW    = (const float*)d_in[16];
  const float* fnB    = (const float*)d_in[17];
  float* out = (float*)d_out;

  char* base = (char*)d_ws; size_t off = 0;
  auto alloc = [&](size_t bytes) {
    void* p = base + off; off = (off + bytes + 255) & ~(size_t)255; return p;
  };
  float* h    = (float*)alloc((size_t)T_ * DM * 4);
  u16*   xzt  = (u16*)  alloc((size_t)2 * DI * T_ * 2);       // [1536][T] bf16
  float* dbl  = (float*)alloc((size_t)2 * T_ * 56 * 4);       // double-buffered
  u16*   yt   = (u16*)  alloc((size_t)DI * T_ * 2);           // [DI][T] bf16
  u16*   imcolF=(u16*)  alloc((size_t)100 * 96 * 128 * 2);    // A-frag, 100 token-panels
  u16*   pwB  = (u16*)  alloc((size_t)DM * 768 * 2);          // frag layout
  u16*   inWb = (u16*)  alloc((size_t)DEPTH_ * 2 * DI * DM * 2);  // frag layout
  u16*   xpWb = (u16*)  alloc((size_t)DEPTH_ * 64 * DI * 2);  // frag layout, padded 56->64
  u16*   outWb= (u16*)  alloc((size_t)DEPTH_ * DM * DI * 2);  // frag layout

  // one-shot: all weights fp32 -> bf16 fragment layout; zero dbl buffers
  repack_kernel<<<dim3((RQ_TOT + 255) / 256), 256, 0, stream>>>(
      patchW, pwB, inW, inWb, xprojW, xpWb, outW, outWb, dbl);

  // patch embed: im2col (frag) + GEMM with fused bias+pos
  imcol_kernel<<<dim3(T_ * 768 / 256), 256, 0, stream>>>(z, x, imcolF);
  gemm_patch<<<dim3((T_ + 63) / 64, DM / 64), 256, 0, stream>>>(
      imcolF, pwB, patchB, pos, h);

  const int TG = (T_ + 63) / 64;  // 25
  for (int ly = 0; ly < DEPTH_; ++ly) {
    int p = ly & 1;
    float* dblc = dbl + (size_t)p * T_ * 56;
    float* dbln = dbl + (size_t)(p ^ 1) * T_ * 56;
    gemm_ln<<<dim3((2 * DI) / 64, TG), 256, 0, stream>>>(
        h, normW + (size_t)ly * DM, normB + (size_t)ly * DM,
        inWb + (size_t)ly * 2 * DI * DM, xzt);
    xproj_conv<<<dim3(TG, 1, DI / XKC), 256, 0, stream>>>(
        xzt, convW + (size_t)ly * DI * 3, convB + (size_t)ly * DI,
        xpWb + (size_t)ly * 64 * DI, dblc);
    scan_kernel<<<dim3(B_ * DI), 448, 0, stream>>>(
        xzt, dblc, convW + (size_t)ly * DI * 3, convB + (size_t)ly * DI,
        dtW + (size_t)ly * DI * DTR, dtB + (size_t)ly * DI,
        Alog + (size_t)ly * DI * DS, Dpar + (size_t)ly * DI, yt, dbln);
    gemm_out<<<dim3(TG, DM / 64, 2), 256, 0, stream>>>(
        yt, outWb + (size_t)ly * DM * DI, h);
  }

  ln_kernel<<<dim3(T_), dim3(DM), 0, stream>>>(h, fnW, fnB, out);
}

// Round 9
// 2359.753 us; speedup vs baseline: 1.0367x; 1.0367x over previous
//
#include <hip/hip_runtime.h>

typedef unsigned short u16;
typedef unsigned int   u32;

#define B_     4
#define L_     392
#define T_     1568   // B_*L_
#define DM     384
#define DI     768
#define DS     16
#define DTR    24
#define DEPTH_ 24
#define NPATCH 196
#define NC     28    // scan chunks
#define CL     14    // chunk length (NC*CL == L_)

// xproj_conv: K-split 8 -> 96 d's per block; LDS row pitch 104 (208B = 13*16B)
#define XKC    96
#define XPAD   104
// gemm_out: K-split 2 -> 384 d's per block; LDS row pitch 392 u16 (784B = 49*16B)
#define OKC    384
#define OPAD   392

typedef __bf16 bf16x8 __attribute__((ext_vector_type(8)));
typedef float  f32x4  __attribute__((ext_vector_type(4)));
typedef u16    u16x4  __attribute__((ext_vector_type(4)));
typedef u16    u16x8  __attribute__((ext_vector_type(8)));

__device__ __forceinline__ u16 f2bf(float f) {
  union { float f; u32 u; } v; v.f = f;
  return (u16)((v.u + 0x7fffu + ((v.u >> 16) & 1u)) >> 16);  // RNE
}
__device__ __forceinline__ float bf2f(u16 h) {
  union { u32 u; float f; } v; v.u = (u32)h << 16; return v.f;
}

// ---------------- one-shot repack: fp32 -> bf16 fragment layout, DST-coalesced ----------------
// Fragment layout per matrix [R rows][K]: dst[ly][p=row/16][kb=k/8][r=row%16][e=k%8].
// Thread i owns dst u16 range [i*8, i*8+8) -> one 16B coalesced store; source side is
// two float4 loads (lanes l and l+16 share a 64B line).
#define RQ0 36864      // patchW: R=384  KB=96  L=1
#define RQ1 1769472    // inW:    R=1536 KB=48  L=24
#define RQ2 147456     // xpW:    Rp=64  KB=96  L=24 (rows 56..63 zero)
#define RQ3 884736     // outW:   R=384  KB=96  L=24
#define RQ4 43904      // dbl zero fill, float4 units
#define RQ_TOT (RQ0+RQ1+RQ2+RQ3+RQ4)

__global__ __launch_bounds__(256) void repack_kernel(
    const float* __restrict__ patchW, u16* __restrict__ pwB,
    const float* __restrict__ inW,    u16* __restrict__ inWb,
    const float* __restrict__ xpW,    u16* __restrict__ xpWb,
    const float* __restrict__ outW,   u16* __restrict__ outWb,
    float* __restrict__ dblz) {
  int i = blockIdx.x * 256 + threadIdx.x;
  const float* sp = nullptr; u16* dp = nullptr;
  if (i < RQ0) {                      // patchW
    int r = i & 15, kb = (i >> 4) % 96, p = i / (16 * 96);
    sp = patchW + (size_t)(p * 16 + r) * 768 + kb * 8;
    dp = pwB + (size_t)i * 8;
  } else { i -= RQ0;
  if (i < RQ1) {                      // inW
    const int per = 1536 * 48;
    int ly = i / per, rem = i - ly * per;
    int r = rem & 15, kb = (rem >> 4) % 48, p = rem / (16 * 48);
    sp = inW + (size_t)ly * 1536 * 384 + (size_t)(p * 16 + r) * 384 + kb * 8;
    dp = inWb + (size_t)i * 8;
  } else { i -= RQ1;
  if (i < RQ2) {                      // xpW (padded rows -> zeros)
    const int per = 64 * 96;
    int ly = i / per, rem = i - ly * per;
    int r = rem & 15, kb = (rem >> 4) % 96, p = rem / (16 * 96);
    int row = p * 16 + r;
    dp = xpWb + (size_t)i * 8;
    if (row < 56) {
      sp = xpW + (size_t)ly * 56 * 768 + (size_t)row * 768 + kb * 8;
    } else {
      u16x8 zz = {0,0,0,0,0,0,0,0};
      *(u16x8*)dp = zz;
      return;
    }
  } else { i -= RQ2;
  if (i < RQ3) {                      // outW
    const int per = 384 * 96;
    int ly = i / per, rem = i - ly * per;
    int r = rem & 15, kb = (rem >> 4) % 96, p = rem / (16 * 96);
    sp = outW + (size_t)ly * 384 * 768 + (size_t)(p * 16 + r) * 768 + kb * 8;
    dp = outWb + (size_t)i * 8;
  } else { i -= RQ3;
  if (i < RQ4) {                      // zero both dbl halves
    ((float4*)dblz)[i] = make_float4(0.f, 0.f, 0.f, 0.f);
  }
  return; } } } }
  float4 a = *(const float4*)sp;
  float4 b = *(const float4*)(sp + 4);
  u16x8 r8;
  r8[0] = f2bf(a.x); r8[1] = f2bf(a.y); r8[2] = f2bf(a.z); r8[3] = f2bf(a.w);
  r8[4] = f2bf(b.x); r8[5] = f2bf(b.y); r8[6] = f2bf(b.z); r8[7] = f2bf(b.w);
  *(u16x8*)dp = r8;
}

// ---------------- im2col for patch embed, emitting A-side fragment layout ----------------
__global__ __launch_bounds__(256) void imcol_kernel(const float* __restrict__ z,
                                                    const float* __restrict__ x,
                                                    u16* __restrict__ out) {
  int idx = blockIdx.x * 256 + threadIdx.x;        // t*768 + k
  int t = idx / 768, k = idx - t * 768;
  int b = t / L_, l = t - b * L_;
  const float* img = (l < NPATCH) ? z : x;
  int p  = (l < NPATCH) ? l : l - NPATCH;
  int py = p / 14, px = p - py * 14;
  int ic = k >> 8, rem = k & 255, i = rem >> 4, j = rem & 15;
  float v = img[((size_t)b * 3 + ic) * 50176 + (size_t)(py * 16 + i) * 224 + (px * 16 + j)];
  size_t o = ((size_t)(t >> 4) * 96 + (k >> 3)) * 128 + (size_t)(t & 15) * 8 + (k & 7);
  out[o] = f2bf(v);
}

// ---------------- patch embed GEMM: both operands fragment-native, no LDS ----------------
// h[t][n] = imcolF(t,:) . pwB(n,:) + patch_b[n] + pos[1 + (t%L)%NPATCH][n]. grid (25, 6).
__global__ __launch_bounds__(256) void gemm_patch(const u16* __restrict__ Af,
                                                  const u16* __restrict__ Wf,
                                                  const float* __restrict__ pb,
                                                  const float* __restrict__ pos,
                                                  float* __restrict__ h) {
  int wave = threadIdx.x >> 6, lane = threadIdx.x & 63;
  int r = lane & 15, quad = lane >> 4;
  int t0 = blockIdx.x * 64;
  int p  = blockIdx.y * 4 + wave;
  const u16* wp  = Wf + ((size_t)p * 96 + quad) * 128 + (size_t)r * 8;
  const u16* ap0 = Af + ((size_t)(t0 >> 4) * 96 + quad) * 128 + (size_t)r * 8;

  f32x4 acc[4] = {f32x4{0,0,0,0}, f32x4{0,0,0,0}, f32x4{0,0,0,0}, f32x4{0,0,0,0}};
#pragma unroll
  for (int k0 = 0; k0 < 768; k0 += 32) {
    bf16x8 bfrag = *(const bf16x8*)(wp + (size_t)(k0 >> 3) * 128);
#pragma unroll
    for (int mi = 0; mi < 4; ++mi) {
      bf16x8 afrag = *(const bf16x8*)(ap0 + ((size_t)mi * 96 + (k0 >> 3)) * 128);
      acc[mi] = __builtin_amdgcn_mfma_f32_16x16x32_bf16(afrag, bfrag, acc[mi], 0, 0, 0);
    }
  }
  int ccol = blockIdx.y * 64 + wave * 16 + r;
  float pbv = pb[ccol];
#pragma unroll
  for (int mi = 0; mi < 4; ++mi) {
#pragma unroll
    for (int rr = 0; rr < 4; ++rr) {
      int crow = t0 + mi * 16 + quad * 4 + rr;
      if (crow < T_) {
        int pp = (crow % L_) % NPATCH;
        h[(size_t)crow * DM + ccol] = acc[mi][rr] + pbv + pos[(size_t)(1 + pp) * DM + ccol];
      }
    }
  }
}

// ---------------- fused LayerNorm + in_proj GEMM (coalesced, frag weights) ----------------
__global__ __launch_bounds__(256) void gemm_ln(const float* __restrict__ h,
                                               const float* __restrict__ lw,
                                               const float* __restrict__ lb,
                                               const u16* __restrict__ W3,
                                               u16* __restrict__ xzt) {
  __shared__ u16 atile[64][392];
  int tid = threadIdx.x;
  int w = tid >> 6, l = tid & 63;
  int tok0 = blockIdx.y * 64;

  const int cA = 4 * l;
  const int cB = 256 + 4 * l;
  float4 wA = *(const float4*)(lw + cA);
  float4 bA = *(const float4*)(lb + cA);
  float4 wB = make_float4(0.f, 0.f, 0.f, 0.f), bB = wB;
  if (l < 32) { wB = *(const float4*)(lw + cB); bB = *(const float4*)(lb + cB); }

#pragma unroll 4
  for (int tt = 0; tt < 16; ++tt) {
    int t = w * 16 + tt;
    int tg = tok0 + t; if (tg > T_ - 1) tg = T_ - 1;
    const float* hrow = h + (size_t)tg * DM;
    float4 a = *(const float4*)(hrow + cA);
    float4 b2 = make_float4(0.f, 0.f, 0.f, 0.f);
    if (l < 32) b2 = *(const float4*)(hrow + cB);
    float s  = a.x + a.y + a.z + a.w + b2.x + b2.y + b2.z + b2.w;
    float s2 = a.x * a.x + a.y * a.y + a.z * a.z + a.w * a.w
             + b2.x * b2.x + b2.y * b2.y + b2.z * b2.z + b2.w * b2.w;
#pragma unroll
    for (int o = 32; o; o >>= 1) { s += __shfl_xor(s, o); s2 += __shfl_xor(s2, o); }
    float mu = s * (1.f / DM);
    float rs = rsqrtf(s2 * (1.f / DM) - mu * mu + 1e-5f);
    u16x4 r4;
    r4.x = f2bf((a.x - mu) * rs * wA.x + bA.x);
    r4.y = f2bf((a.y - mu) * rs * wA.y + bA.y);
    r4.z = f2bf((a.z - mu) * rs * wA.z + bA.z);
    r4.w = f2bf((a.w - mu) * rs * wA.w + bA.w);
    *(u16x4*)&atile[t][cA] = r4;
    if (l < 32) {
      u16x4 r4b;
      r4b.x = f2bf((b2.x - mu) * rs * wB.x + bB.x);
      r4b.y = f2bf((b2.y - mu) * rs * wB.y + bB.y);
      r4b.z = f2bf((b2.z - mu) * rs * wB.z + bB.z);
      r4b.w = f2bf((b2.w - mu) * rs * wB.w + bB.w);
      *(u16x4*)&atile[t][cB] = r4b;
    }
  }
  __syncthreads();

  int r = l & 15, u = l >> 4;
  int pbase = blockIdx.x * 4;
  const u16* wp = W3 + ((size_t)pbase * 48 + (size_t)u) * 128 + (size_t)r * 8;
  const u16* lp = &atile[w * 16 + r][u * 8];

  f32x4 acc[4] = {f32x4{0,0,0,0}, f32x4{0,0,0,0}, f32x4{0,0,0,0}, f32x4{0,0,0,0}};
#pragma unroll
  for (int k0 = 0; k0 < DM; k0 += 32) {
    bf16x8 bfrag = *(const bf16x8*)(lp + k0);
#pragma unroll
    for (int mi = 0; mi < 4; ++mi) {
      bf16x8 afrag = *(const bf16x8*)(wp + ((size_t)mi * 48 + (k0 >> 3)) * 128);
      acc[mi] = __builtin_amdgcn_mfma_f32_16x16x32_bf16(afrag, bfrag, acc[mi], 0, 0, 0);
    }
  }
  int ccol = tok0 + w * 16 + r;
  if (ccol < T_) {
#pragma unroll
    for (int mi = 0; mi < 4; ++mi) {
#pragma unroll
      for (int rr2 = 0; rr2 < 4; ++rr2) {
        int crow = pbase * 16 + mi * 16 + u * 4 + rr2;
        xzt[(size_t)crow * T_ + ccol] = f2bf(acc[mi][rr2]);
      }
    }
  }
}

// ---------------- fused conv3+SiLU + x_proj GEMM (frag weights) ----------------
// dbl[T,56] += conv(xzt)·xpW^T over d-slice. grid (25, 1, 8), atomic epilogue.
__global__ __launch_bounds__(256) void xproj_conv(const u16* __restrict__ xzt,
                                                  const float* __restrict__ cw,
                                                  const float* __restrict__ cb,
                                                  const u16* __restrict__ Wx3,
                                                  float* __restrict__ dbl) {
  __shared__ u16 tile[64][XPAD];
  int t0 = blockIdx.x * 64;
  int kbeg = blockIdx.z * XKC;
  int tid = threadIdx.x;
  int tl = tid & 63, rq = tid >> 6;
  int t = t0 + tl;
  int tc = (t < T_) ? t : T_ - 1;
  int l = tc % L_;
  for (int kkb = rq * 2; kkb < XKC; kkb += 8) {
    u32 pack = 0;
#pragma unroll
    for (int ss = 0; ss < 2; ++ss) {
      int d = kbeg + kkb + ss;
      const u16* row = xzt + (size_t)d * T_ + tc;
      float acc = cb[d] + cw[d * 3 + 2] * bf2f(row[0]);
      if (l >= 1) acc += cw[d * 3 + 1] * bf2f(row[-1]);
      if (l >= 2) acc += cw[d * 3 + 0] * bf2f(row[-2]);
      float v = acc / (1.f + __expf(-acc));
      pack |= (u32)f2bf(v) << (16 * ss);
    }
    *(u32*)&tile[tl][kkb] = pack;
  }
  __syncthreads();

  int wave = tid >> 6, lane = tid & 63;
  int r = lane & 15, quad = lane >> 4;
  int wcol = wave * 16 + r;
  const u16* wp = Wx3 + ((size_t)wave * 96 + (kbeg >> 3) + quad) * 128 + (size_t)r * 8;

  f32x4 acc4[4] = {f32x4{0,0,0,0}, f32x4{0,0,0,0}, f32x4{0,0,0,0}, f32x4{0,0,0,0}};
#pragma unroll
  for (int k0 = 0; k0 < XKC; k0 += 32) {
    bf16x8 bfrag = *(const bf16x8*)(wp + (size_t)(k0 >> 3) * 128);
#pragma unroll
    for (int mi = 0; mi < 4; ++mi) {
      bf16x8 afrag = *(const bf16x8*)&tile[mi * 16 + r][k0 + quad * 8];
      acc4[mi] = __builtin_amdgcn_mfma_f32_16x16x32_bf16(afrag, bfrag, acc4[mi], 0, 0, 0);
    }
  }
  if (wcol < 56) {
#pragma unroll
    for (int mi = 0; mi < 4; ++mi) {
#pragma unroll
      for (int rr = 0; rr < 4; ++rr) {
        int crow = t0 + mi * 16 + quad * 4 + rr;
        if (crow < T_) atomicAdd(&dbl[(size_t)crow * 56 + wcol], acc4[mi][rr]);
      }
    }
  }
}

// ---------------- fused transpose + out_proj GEMM (frag weights, K-split 2) ----------------
// h[T,384] += y^T·outW^T over d-slice. grid (25, 6, 2), atomic epilogue.
__global__ __launch_bounds__(256) void gemm_out(const u16* __restrict__ yt,
                                                const u16* __restrict__ Wo3,
                                                float* __restrict__ h) {
  __shared__ u16 tile[64][OPAD];
  int t0 = blockIdx.x * 64;
  int kbeg = blockIdx.z * OKC;
  int tid = threadIdx.x;
  {
    int tl2 = tid & 31, rq = tid >> 5;   // 8 rows per pass
    for (int kk = rq; kk < OKC; kk += 8) {
      int d = kbeg + kk;
      u32 v = *(const u32*)(yt + (size_t)d * T_ + t0 + tl2 * 2);
      tile[tl2 * 2][kk]     = (u16)v;
      tile[tl2 * 2 + 1][kk] = (u16)(v >> 16);
    }
  }
  __syncthreads();

  int wave = tid >> 6, lane = tid & 63;
  int r = lane & 15, quad = lane >> 4;
  int p = blockIdx.y * 4 + wave;
  const u16* wp = Wo3 + ((size_t)p * 96 + (kbeg >> 3) + quad) * 128 + (size_t)r * 8;

  f32x4 acc[4] = {f32x4{0,0,0,0}, f32x4{0,0,0,0}, f32x4{0,0,0,0}, f32x4{0,0,0,0}};
#pragma unroll
  for (int k0 = 0; k0 < OKC; k0 += 32) {
    bf16x8 bfrag = *(const bf16x8*)(wp + (size_t)(k0 >> 3) * 128);
#pragma unroll
    for (int mi = 0; mi < 4; ++mi) {
      bf16x8 afrag = *(const bf16x8*)&tile[mi * 16 + r][k0 + quad * 8];
      acc[mi] = __builtin_amdgcn_mfma_f32_16x16x32_bf16(afrag, bfrag, acc[mi], 0, 0, 0);
    }
  }
  int ccol = blockIdx.y * 64 + wave * 16 + r;
#pragma unroll
  for (int mi = 0; mi < 4; ++mi) {
#pragma unroll
    for (int rr = 0; rr < 4; ++rr) {
      int crow = t0 + mi * 16 + quad * 4 + rr;
      if (crow < T_) atomicAdd(&h[(size_t)crow * DM + ccol], acc[mi][rr]);
    }
  }
}

// ---------------- LayerNorm over DM per token (final only) ----------------
__global__ __launch_bounds__(384) void ln_kernel(const float* __restrict__ x,
                                                 const float* __restrict__ w,
                                                 const float* __restrict__ b,
                                                 float* __restrict__ out_f) {
  int t = blockIdx.x;
  int i = threadIdx.x;
  float v = x[(size_t)t * DM + i];
  float s = v, s2 = v * v;
#pragma unroll
  for (int o = 32; o; o >>= 1) { s += __shfl_xor(s, o); s2 += __shfl_xor(s2, o); }
  __shared__ float ls[6], ls2[6];
  int wv = i >> 6;
  if ((i & 63) == 0) { ls[wv] = s; ls2[wv] = s2; }
  __syncthreads();
  float ts = 0.f, ts2 = 0.f;
#pragma unroll
  for (int j = 0; j < 6; ++j) { ts += ls[j]; ts2 += ls2[j]; }
  float mu  = ts * (1.f / DM);
  float var = ts2 * (1.f / DM) - mu * mu;
  float rs  = rsqrtf(var + 1e-5f);
  out_f[(size_t)t * DM + i] = (v - mu) * rs * w[i] + b[i];
}

// ---------------- chunked selective scan v10: low-LDS shuffle-reduce ----------------
// Round-6 structure (3072 blocks, vectorized dt-dot) with the 26.7KB hC transpose
// array replaced by an intra-wave shuffle reduction: the 16 n-values of each (c,l)
// live in 16 consecutive lanes (tid=c*16+n), so the n-sum is 4x __shfl_xor (DPP,
// conflict-free); lane n==0 writes a 1.6KB ysh. LDS 36.9 -> ~11.6KB -> 4 blocks/CU
// (was ~2, measured OccupancyPercent 41.7 in r8 profile).
__global__ __launch_bounds__(448) void scan_kernel(const u16* __restrict__ xzt,
                                                   const float* __restrict__ dbl,
                                                   const float* __restrict__ cw,
                                                   const float* __restrict__ cb,
                                                   const float* __restrict__ dtW,
                                                   const float* __restrict__ dtB,
                                                   const float* __restrict__ Alog,
                                                   const float* __restrict__ Dp,
                                                   u16* __restrict__ yt,
                                                   float* __restrict__ dblz) {
  int bd = blockIdx.x;          // b*DI + d
  int d  = bd % DI;
  int b  = bd / DI;
  int tid = threadIdx.x;
  int n = tid & 15, c = tid >> 4;   // c in [0,28)

  __shared__ float dtsh[L_];
  __shared__ float zsh[L_];
  __shared__ float xcsh[L_];
  __shared__ float ysh[L_];
  __shared__ float Psh[NC][DS], Ssh[NC][DS], Hsh[NC][DS];

  // zero slice of next dbl buffer (29 floats per block)
  {
    int i0 = blockIdx.x * 29 + tid;
    if (tid < 29 && i0 < T_ * 56) dblz[i0] = 0.f;
  }

  // cooperative: conv row (recompute), dt projection + softplus, silu(z) — one pass
  const float* wr = dtW + (size_t)d * DTR;   // block-uniform -> scalar loads
  float bias = dtB[d];
  float w0 = cw[d * 3 + 0], w1 = cw[d * 3 + 1], w2 = cw[d * 3 + 2], cbd = cb[d];
  const u16* xrow = xzt + (size_t)d * T_ + b * L_;
  const u16* zrow = xzt + (size_t)(DI + d) * T_ + b * L_;
  if (tid < L_) {
    int l = tid;
    const float4* dr4 = (const float4*)(dbl + (size_t)(b * L_ + l) * 56);
    float s = bias;
#pragma unroll
    for (int j = 0; j < 6; ++j) {
      float4 dv = dr4[j];
      s += dv.x * wr[j * 4 + 0] + dv.y * wr[j * 4 + 1]
         + dv.z * wr[j * 4 + 2] + dv.w * wr[j * 4 + 3];
    }
    dtsh[l] = (s > 20.f) ? s : log1pf(__expf(s));
    float zv = bf2f(zrow[l]);
    zsh[l] = zv / (1.f + __expf(-zv));
    float a = cbd + w2 * bf2f(xrow[l]);
    if (l >= 1) a += w1 * bf2f(xrow[l - 1]);
    if (l >= 2) a += w0 * bf2f(xrow[l - 2]);
    xcsh[l] = a / (1.f + __expf(-a));
  }
  float A  = -__expf(Alog[(size_t)d * DS + n]);
  float Dd = Dp[d];
  __syncthreads();

  int tb = b * L_ + c * CL;
  const float* Bp = dbl + (size_t)tb * 56 + DTR + n;
  const float* Cp = Bp + DS;

  float dA[CL], dBu[CL];
  {
    float P = 1.f, S = 0.f;
#pragma unroll
    for (int l = 0; l < CL; ++l) {
      float dtv = dtsh[c * CL + l];
      float xcv = xcsh[c * CL + l];
      float Bv  = Bp[l * 56];
      float e = __expf(dtv * A);
      float u = dtv * xcv * Bv;
      dA[l] = e; dBu[l] = u;
      P *= e;
      S = e * S + u;
    }
    Psh[c][n] = P; Ssh[c][n] = S;
  }
  __syncthreads();
  if (tid < DS) {   // thread n: serial combine over 28 chunks
    float hh = 0.f;
#pragma unroll
    for (int cc = 0; cc < NC; ++cc) {
      Hsh[cc][tid] = hh;
      hh = Psh[cc][tid] * hh + Ssh[cc][tid];
    }
  }
  __syncthreads();
  {
    float hh = Hsh[c][n];
#pragma unroll
    for (int l = 0; l < CL; ++l) {
      hh = dA[l] * hh + dBu[l];
      float v = hh * Cp[l * 56];
      v += __shfl_xor(v, 1);
      v += __shfl_xor(v, 2);
      v += __shfl_xor(v, 4);
      v += __shfl_xor(v, 8);
      if (n == 0) ysh[c * CL + l] = v;
    }
  }
  __syncthreads();
  if (tid < L_) {   // thread l: gate, coalesced y store
    int l = tid;
    yt[(size_t)d * T_ + b * L_ + l] = f2bf((ysh[l] + Dd * xcsh[l]) * zsh[l]);
  }
}

extern "C" void kernel_launch(void* const* d_in, const int* in_sizes, int n_in,
                              void* d_out, int out_size, void* d_ws, size_t ws_size,
                              hipStream_t stream) {
  const float* z      = (const float*)d_in[0];
  const float* x      = (const float*)d_in[1];
  const float* patchW = (const float*)d_in[2];
  const float* patchB = (const float*)d_in[3];
  const float* pos    = (const float*)d_in[4];
  const float* normW  = (const float*)d_in[5];
  const float* normB  = (const float*)d_in[6];
  const float* inW    = (const float*)d_in[7];
  const float* convW  = (const float*)d_in[8];
  const float* convB  = (const float*)d_in[9];
  const float* xprojW = (const float*)d_in[10];
  const float* dtW    = (const float*)d_in[11];
  const float* dtB    = (const float*)d_in[12];
  const float* Alog   = (const float*)d_in[13];
  const float* Dpar   = (const float*)d_in[14];
  const float* outW   = (const float*)d_in[15];
  const float* fnW    = (const float*)d_in[16];
  const float* fnB    = (const float*)d_in[17];
  float* out = (float*)d_out;

  char* base = (char*)d_ws; size_t off = 0;
  auto alloc = [&](size_t bytes) {
    void* p = base + off; off = (off + bytes + 255) & ~(size_t)255; return p;
  };
  float* h    = (float*)alloc((size_t)T_ * DM * 4);
  u16*   xzt  = (u16*)  alloc((size_t)2 * DI * T_ * 2);       // [1536][T] bf16
  float* dbl  = (float*)alloc((size_t)2 * T_ * 56 * 4);       // double-buffered
  u16*   yt   = (u16*)  alloc((size_t)DI * T_ * 2);           // [DI][T] bf16
  u16*   imcolF=(u16*)  alloc((size_t)100 * 96 * 128 * 2);    // A-frag, 100 token-panels
  u16*   pwB  = (u16*)  alloc((size_t)DM * 768 * 2);          // frag layout
  u16*   inWb = (u16*)  alloc((size_t)DEPTH_ * 2 * DI * DM * 2);  // frag layout
  u16*   xpWb = (u16*)  alloc((size_t)DEPTH_ * 64 * DI * 2);  // frag layout, padded 56->64
  u16*   outWb= (u16*)  alloc((size_t)DEPTH_ * DM * DI * 2);  // frag layout

  // one-shot: all weights fp32 -> bf16 fragment layout; zero dbl buffers
  repack_kernel<<<dim3((RQ_TOT + 255) / 256), 256, 0, stream>>>(
      patchW, pwB, inW, inWb, xprojW, xpWb, outW, outWb, dbl);

  // patch embed: im2col (frag) + GEMM with fused bias+pos
  imcol_kernel<<<dim3(T_ * 768 / 256), 256, 0, stream>>>(z, x, imcolF);
  gemm_patch<<<dim3((T_ + 63) / 64, DM / 64), 256, 0, stream>>>(
      imcolF, pwB, patchB, pos, h);

  const int TG = (T_ + 63) / 64;  // 25
  for (int ly = 0; ly < DEPTH_; ++ly) {
    int p = ly & 1;
    float* dblc = dbl + (size_t)p * T_ * 56;
    float* dbln = dbl + (size_t)(p ^ 1) * T_ * 56;
    gemm_ln<<<dim3((2 * DI) / 64, TG), 256, 0, stream>>>(
        h, normW + (size_t)ly * DM, normB + (size_t)ly * DM,
        inWb + (size_t)ly * 2 * DI * DM, xzt);
    xproj_conv<<<dim3(TG, 1, DI / XKC), 256, 0, stream>>>(
        xzt, convW + (size_t)ly * DI * 3, convB + (size_t)ly * DI,
        xpWb + (size_t)ly * 64 * DI, dblc);
    scan_kernel<<<dim3(B_ * DI), 448, 0, stream>>>(
        xzt, dblc, convW + (size_t)ly * DI * 3, convB + (size_t)ly * DI,
        dtW + (size_t)ly * DI * DTR, dtB + (size_t)ly * DI,
        Alog + (size_t)ly * DI * DS, Dpar + (size_t)ly * DI, yt, dbln);
    gemm_out<<<dim3(TG, DM / 64, 2), 256, 0, stream>>>(
        yt, outWb + (size_t)ly * DM * DI, h);
  }

  ln_kernel<<<dim3(T_), dim3(DM), 0, stream>>>(h, fnW, fnB, out);
}

// Round 10
// 2078.998 us; speedup vs baseline: 1.1767x; 1.1350x over previous
//
#include <hip/hip_runtime.h>

typedef unsigned short u16;
typedef unsigned int   u32;

#define B_     4
#define L_     392
#define T_     1568   // B_*L_
#define DM     384
#define DI     768
#define DS     16
#define DTR    24
#define DEPTH_ 24
#define NPATCH 196
#define NC     28    // scan chunks
#define CL     14    // chunk length (NC*CL == L_)

// xproj_conv: K-split 8 -> 96 d's per block; LDS row pitch 104 (208B = 13*16B)
#define XKC    96
#define XPAD   104
// gemm_out: K-split 2 -> 384 d's per block; LDS row pitch 392 u16 (784B = 49*16B)
#define OKC    384
#define OPAD   392

typedef __bf16 bf16x8 __attribute__((ext_vector_type(8)));
typedef float  f32x4  __attribute__((ext_vector_type(4)));
typedef u16    u16x4  __attribute__((ext_vector_type(4)));
typedef u16    u16x8  __attribute__((ext_vector_type(8)));

__device__ __forceinline__ u16 f2bf(float f) {
  union { float f; u32 u; } v; v.f = f;
  return (u16)((v.u + 0x7fffu + ((v.u >> 16) & 1u)) >> 16);  // RNE
}
__device__ __forceinline__ float bf2f(u16 h) {
  union { u32 u; float f; } v; v.u = (u32)h << 16; return v.f;
}

// ---------------- one-shot repack: fp32 -> bf16 fragment layout, DST-coalesced ----------------
// Fragment layout per matrix [R rows][K]: dst[ly][p=row/16][kb=k/8][r=row%16][e=k%8].
// Thread i owns dst u16 range [i*8, i*8+8) -> one 16B coalesced store; source side is
// two float4 loads (lanes l and l+16 share a 64B line).
#define RQ0 36864      // patchW: R=384  KB=96  L=1
#define RQ1 1769472    // inW:    R=1536 KB=48  L=24
#define RQ2 147456     // xpW:    Rp=64  KB=96  L=24 (rows 56..63 zero)
#define RQ3 884736     // outW:   R=384  KB=96  L=24
#define RQ4 43904      // dbl zero fill, float4 units
#define RQ_TOT (RQ0+RQ1+RQ2+RQ3+RQ4)

__global__ __launch_bounds__(256) void repack_kernel(
    const float* __restrict__ patchW, u16* __restrict__ pwB,
    const float* __restrict__ inW,    u16* __restrict__ inWb,
    const float* __restrict__ xpW,    u16* __restrict__ xpWb,
    const float* __restrict__ outW,   u16* __restrict__ outWb,
    float* __restrict__ dblz) {
  int i = blockIdx.x * 256 + threadIdx.x;
  const float* sp = nullptr; u16* dp = nullptr;
  if (i < RQ0) {                      // patchW
    int r = i & 15, kb = (i >> 4) % 96, p = i / (16 * 96);
    sp = patchW + (size_t)(p * 16 + r) * 768 + kb * 8;
    dp = pwB + (size_t)i * 8;
  } else { i -= RQ0;
  if (i < RQ1) {                      // inW
    const int per = 1536 * 48;
    int ly = i / per, rem = i - ly * per;
    int r = rem & 15, kb = (rem >> 4) % 48, p = rem / (16 * 48);
    sp = inW + (size_t)ly * 1536 * 384 + (size_t)(p * 16 + r) * 384 + kb * 8;
    dp = inWb + (size_t)i * 8;
  } else { i -= RQ1;
  if (i < RQ2) {                      // xpW (padded rows -> zeros)
    const int per = 64 * 96;
    int ly = i / per, rem = i - ly * per;
    int r = rem & 15, kb = (rem >> 4) % 96, p = rem / (16 * 96);
    int row = p * 16 + r;
    dp = xpWb + (size_t)i * 8;
    if (row < 56) {
      sp = xpW + (size_t)ly * 56 * 768 + (size_t)row * 768 + kb * 8;
    } else {
      u16x8 zz = {0,0,0,0,0,0,0,0};
      *(u16x8*)dp = zz;
      return;
    }
  } else { i -= RQ2;
  if (i < RQ3) {                      // outW
    const int per = 384 * 96;
    int ly = i / per, rem = i - ly * per;
    int r = rem & 15, kb = (rem >> 4) % 96, p = rem / (16 * 96);
    sp = outW + (size_t)ly * 384 * 768 + (size_t)(p * 16 + r) * 768 + kb * 8;
    dp = outWb + (size_t)i * 8;
  } else { i -= RQ3;
  if (i < RQ4) {                      // zero both dbl halves
    ((float4*)dblz)[i] = make_float4(0.f, 0.f, 0.f, 0.f);
  }
  return; } } } }
  float4 a = *(const float4*)sp;
  float4 b = *(const float4*)(sp + 4);
  u16x8 r8;
  r8[0] = f2bf(a.x); r8[1] = f2bf(a.y); r8[2] = f2bf(a.z); r8[3] = f2bf(a.w);
  r8[4] = f2bf(b.x); r8[5] = f2bf(b.y); r8[6] = f2bf(b.z); r8[7] = f2bf(b.w);
  *(u16x8*)dp = r8;
}

// ---------------- im2col for patch embed, emitting A-side fragment layout ----------------
__global__ __launch_bounds__(256) void imcol_kernel(const float* __restrict__ z,
                                                    const float* __restrict__ x,
                                                    u16* __restrict__ out) {
  int idx = blockIdx.x * 256 + threadIdx.x;        // t*768 + k
  int t = idx / 768, k = idx - t * 768;
  int b = t / L_, l = t - b * L_;
  const float* img = (l < NPATCH) ? z : x;
  int p  = (l < NPATCH) ? l : l - NPATCH;
  int py = p / 14, px = p - py * 14;
  int ic = k >> 8, rem = k & 255, i = rem >> 4, j = rem & 15;
  float v = img[((size_t)b * 3 + ic) * 50176 + (size_t)(py * 16 + i) * 224 + (px * 16 + j)];
  size_t o = ((size_t)(t >> 4) * 96 + (k >> 3)) * 128 + (size_t)(t & 15) * 8 + (k & 7);
  out[o] = f2bf(v);
}

// ---------------- patch embed GEMM: both operands fragment-native, no LDS ----------------
// h[t][n] = imcolF(t,:) . pwB(n,:) + patch_b[n] + pos[1 + (t%L)%NPATCH][n]. grid (25, 6).
__global__ __launch_bounds__(256) void gemm_patch(const u16* __restrict__ Af,
                                                  const u16* __restrict__ Wf,
                                                  const float* __restrict__ pb,
                                                  const float* __restrict__ pos,
                                                  float* __restrict__ h) {
  int wave = threadIdx.x >> 6, lane = threadIdx.x & 63;
  int r = lane & 15, quad = lane >> 4;
  int t0 = blockIdx.x * 64;
  int p  = blockIdx.y * 4 + wave;
  const u16* wp  = Wf + ((size_t)p * 96 + quad) * 128 + (size_t)r * 8;
  const u16* ap0 = Af + ((size_t)(t0 >> 4) * 96 + quad) * 128 + (size_t)r * 8;

  f32x4 acc[4] = {f32x4{0,0,0,0}, f32x4{0,0,0,0}, f32x4{0,0,0,0}, f32x4{0,0,0,0}};
#pragma unroll
  for (int k0 = 0; k0 < 768; k0 += 32) {
    bf16x8 bfrag = *(const bf16x8*)(wp + (size_t)(k0 >> 3) * 128);
#pragma unroll
    for (int mi = 0; mi < 4; ++mi) {
      bf16x8 afrag = *(const bf16x8*)(ap0 + ((size_t)mi * 96 + (k0 >> 3)) * 128);
      acc[mi] = __builtin_amdgcn_mfma_f32_16x16x32_bf16(afrag, bfrag, acc[mi], 0, 0, 0);
    }
  }
  int ccol = blockIdx.y * 64 + wave * 16 + r;
  float pbv = pb[ccol];
#pragma unroll
  for (int mi = 0; mi < 4; ++mi) {
#pragma unroll
    for (int rr = 0; rr < 4; ++rr) {
      int crow = t0 + mi * 16 + quad * 4 + rr;
      if (crow < T_) {
        int pp = (crow % L_) % NPATCH;
        h[(size_t)crow * DM + ccol] = acc[mi][rr] + pbv + pos[(size_t)(1 + pp) * DM + ccol];
      }
    }
  }
}

// ---------------- fused LayerNorm + in_proj GEMM (coalesced, frag weights) ----------------
__global__ __launch_bounds__(256) void gemm_ln(const float* __restrict__ h,
                                               const float* __restrict__ lw,
                                               const float* __restrict__ lb,
                                               const u16* __restrict__ W3,
                                               u16* __restrict__ xzt) {
  __shared__ u16 atile[64][392];
  int tid = threadIdx.x;
  int w = tid >> 6, l = tid & 63;
  int tok0 = blockIdx.y * 64;

  const int cA = 4 * l;
  const int cB = 256 + 4 * l;
  float4 wA = *(const float4*)(lw + cA);
  float4 bA = *(const float4*)(lb + cA);
  float4 wB = make_float4(0.f, 0.f, 0.f, 0.f), bB = wB;
  if (l < 32) { wB = *(const float4*)(lw + cB); bB = *(const float4*)(lb + cB); }

#pragma unroll 4
  for (int tt = 0; tt < 16; ++tt) {
    int t = w * 16 + tt;
    int tg = tok0 + t; if (tg > T_ - 1) tg = T_ - 1;
    const float* hrow = h + (size_t)tg * DM;
    float4 a = *(const float4*)(hrow + cA);
    float4 b2 = make_float4(0.f, 0.f, 0.f, 0.f);
    if (l < 32) b2 = *(const float4*)(hrow + cB);
    float s  = a.x + a.y + a.z + a.w + b2.x + b2.y + b2.z + b2.w;
    float s2 = a.x * a.x + a.y * a.y + a.z * a.z + a.w * a.w
             + b2.x * b2.x + b2.y * b2.y + b2.z * b2.z + b2.w * b2.w;
#pragma unroll
    for (int o = 32; o; o >>= 1) { s += __shfl_xor(s, o); s2 += __shfl_xor(s2, o); }
    float mu = s * (1.f / DM);
    float rs = rsqrtf(s2 * (1.f / DM) - mu * mu + 1e-5f);
    u16x4 r4;
    r4.x = f2bf((a.x - mu) * rs * wA.x + bA.x);
    r4.y = f2bf((a.y - mu) * rs * wA.y + bA.y);
    r4.z = f2bf((a.z - mu) * rs * wA.z + bA.z);
    r4.w = f2bf((a.w - mu) * rs * wA.w + bA.w);
    *(u16x4*)&atile[t][cA] = r4;
    if (l < 32) {
      u16x4 r4b;
      r4b.x = f2bf((b2.x - mu) * rs * wB.x + bB.x);
      r4b.y = f2bf((b2.y - mu) * rs * wB.y + bB.y);
      r4b.z = f2bf((b2.z - mu) * rs * wB.z + bB.z);
      r4b.w = f2bf((b2.w - mu) * rs * wB.w + bB.w);
      *(u16x4*)&atile[t][cB] = r4b;
    }
  }
  __syncthreads();

  int r = l & 15, u = l >> 4;
  int pbase = blockIdx.x * 4;
  const u16* wp = W3 + ((size_t)pbase * 48 + (size_t)u) * 128 + (size_t)r * 8;
  const u16* lp = &atile[w * 16 + r][u * 8];

  f32x4 acc[4] = {f32x4{0,0,0,0}, f32x4{0,0,0,0}, f32x4{0,0,0,0}, f32x4{0,0,0,0}};
#pragma unroll
  for (int k0 = 0; k0 < DM; k0 += 32) {
    bf16x8 bfrag = *(const bf16x8*)(lp + k0);
#pragma unroll
    for (int mi = 0; mi < 4; ++mi) {
      bf16x8 afrag = *(const bf16x8*)(wp + ((size_t)mi * 48 + (k0 >> 3)) * 128);
      acc[mi] = __builtin_amdgcn_mfma_f32_16x16x32_bf16(afrag, bfrag, acc[mi], 0, 0, 0);
    }
  }
  int ccol = tok0 + w * 16 + r;
  if (ccol < T_) {
#pragma unroll
    for (int mi = 0; mi < 4; ++mi) {
#pragma unroll
      for (int rr2 = 0; rr2 < 4; ++rr2) {
        int crow = pbase * 16 + mi * 16 + u * 4 + rr2;
        xzt[(size_t)crow * T_ + ccol] = f2bf(acc[mi][rr2]);
      }
    }
  }
}

// ---------------- fused conv3+SiLU + x_proj GEMM (frag weights) ----------------
// dbl[T,56] += conv(xzt)·xpW^T over d-slice. grid (25, 1, 8), atomic epilogue.
__global__ __launch_bounds__(256) void xproj_conv(const u16* __restrict__ xzt,
                                                  const float* __restrict__ cw,
                                                  const float* __restrict__ cb,
                                                  const u16* __restrict__ Wx3,
                                                  float* __restrict__ dbl) {
  __shared__ u16 tile[64][XPAD];
  int t0 = blockIdx.x * 64;
  int kbeg = blockIdx.z * XKC;
  int tid = threadIdx.x;
  int tl = tid & 63, rq = tid >> 6;
  int t = t0 + tl;
  int tc = (t < T_) ? t : T_ - 1;
  int l = tc % L_;
  for (int kkb = rq * 2; kkb < XKC; kkb += 8) {
    u32 pack = 0;
#pragma unroll
    for (int ss = 0; ss < 2; ++ss) {
      int d = kbeg + kkb + ss;
      const u16* row = xzt + (size_t)d * T_ + tc;
      float acc = cb[d] + cw[d * 3 + 2] * bf2f(row[0]);
      if (l >= 1) acc += cw[d * 3 + 1] * bf2f(row[-1]);
      if (l >= 2) acc += cw[d * 3 + 0] * bf2f(row[-2]);
      float v = acc / (1.f + __expf(-acc));
      pack |= (u32)f2bf(v) << (16 * ss);
    }
    *(u32*)&tile[tl][kkb] = pack;
  }
  __syncthreads();

  int wave = tid >> 6, lane = tid & 63;
  int r = lane & 15, quad = lane >> 4;
  int wcol = wave * 16 + r;
  const u16* wp = Wx3 + ((size_t)wave * 96 + (kbeg >> 3) + quad) * 128 + (size_t)r * 8;

  f32x4 acc4[4] = {f32x4{0,0,0,0}, f32x4{0,0,0,0}, f32x4{0,0,0,0}, f32x4{0,0,0,0}};
#pragma unroll
  for (int k0 = 0; k0 < XKC; k0 += 32) {
    bf16x8 bfrag = *(const bf16x8*)(wp + (size_t)(k0 >> 3) * 128);
#pragma unroll
    for (int mi = 0; mi < 4; ++mi) {
      bf16x8 afrag = *(const bf16x8*)&tile[mi * 16 + r][k0 + quad * 8];
      acc4[mi] = __builtin_amdgcn_mfma_f32_16x16x32_bf16(afrag, bfrag, acc4[mi], 0, 0, 0);
    }
  }
  if (wcol < 56) {
#pragma unroll
    for (int mi = 0; mi < 4; ++mi) {
#pragma unroll
      for (int rr = 0; rr < 4; ++rr) {
        int crow = t0 + mi * 16 + quad * 4 + rr;
        if (crow < T_) atomicAdd(&dbl[(size_t)crow * 56 + wcol], acc4[mi][rr]);
      }
    }
  }
}

// ---------------- fused transpose + out_proj GEMM (frag weights, K-split 2) ----------------
// h[T,384] += y^T·outW^T over d-slice. grid (25, 6, 2), atomic epilogue.
__global__ __launch_bounds__(256) void gemm_out(const u16* __restrict__ yt,
                                                const u16* __restrict__ Wo3,
                                                float* __restrict__ h) {
  __shared__ u16 tile[64][OPAD];
  int t0 = blockIdx.x * 64;
  int kbeg = blockIdx.z * OKC;
  int tid = threadIdx.x;
  {
    int tl2 = tid & 31, rq = tid >> 5;   // 8 rows per pass
    for (int kk = rq; kk < OKC; kk += 8) {
      int d = kbeg + kk;
      u32 v = *(const u32*)(yt + (size_t)d * T_ + t0 + tl2 * 2);
      tile[tl2 * 2][kk]     = (u16)v;
      tile[tl2 * 2 + 1][kk] = (u16)(v >> 16);
    }
  }
  __syncthreads();

  int wave = tid >> 6, lane = tid & 63;
  int r = lane & 15, quad = lane >> 4;
  int p = blockIdx.y * 4 + wave;
  const u16* wp = Wo3 + ((size_t)p * 96 + (kbeg >> 3) + quad) * 128 + (size_t)r * 8;

  f32x4 acc[4] = {f32x4{0,0,0,0}, f32x4{0,0,0,0}, f32x4{0,0,0,0}, f32x4{0,0,0,0}};
#pragma unroll
  for (int k0 = 0; k0 < OKC; k0 += 32) {
    bf16x8 bfrag = *(const bf16x8*)(wp + (size_t)(k0 >> 3) * 128);
#pragma unroll
    for (int mi = 0; mi < 4; ++mi) {
      bf16x8 afrag = *(const bf16x8*)&tile[mi * 16 + r][k0 + quad * 8];
      acc[mi] = __builtin_amdgcn_mfma_f32_16x16x32_bf16(afrag, bfrag, acc[mi], 0, 0, 0);
    }
  }
  int ccol = blockIdx.y * 64 + wave * 16 + r;
#pragma unroll
  for (int mi = 0; mi < 4; ++mi) {
#pragma unroll
    for (int rr = 0; rr < 4; ++rr) {
      int crow = t0 + mi * 16 + quad * 4 + rr;
      if (crow < T_) atomicAdd(&h[(size_t)crow * DM + ccol], acc[mi][rr]);
    }
  }
}

// ---------------- LayerNorm over DM per token (final only) ----------------
__global__ __launch_bounds__(384) void ln_kernel(const float* __restrict__ x,
                                                 const float* __restrict__ w,
                                                 const float* __restrict__ b,
                                                 float* __restrict__ out_f) {
  int t = blockIdx.x;
  int i = threadIdx.x;
  float v = x[(size_t)t * DM + i];
  float s = v, s2 = v * v;
#pragma unroll
  for (int o = 32; o; o >>= 1) { s += __shfl_xor(s, o); s2 += __shfl_xor(s2, o); }
  __shared__ float ls[6], ls2[6];
  int wv = i >> 6;
  if ((i & 63) == 0) { ls[wv] = s; ls2[wv] = s2; }
  __syncthreads();
  float ts = 0.f, ts2 = 0.f;
#pragma unroll
  for (int j = 0; j < 6; ++j) { ts += ls[j]; ts2 += ls2[j]; }
  float mu  = ts * (1.f / DM);
  float var = ts2 * (1.f / DM) - mu * mu;
  float rs  = rsqrtf(var + 1e-5f);
  out_f[(size_t)t * DM + i] = (v - mu) * rs * w[i] + b[i];
}

// ---------------- chunked selective scan v11: redundant prefix fold, 3 barriers ----------------
// Round-6 structure (best measured: 3072 blocks, vectorized dt-dot, hC transpose) with
// the 16-thread serial chunk-combine + its barrier REMOVED: each thread (c,n) folds
// Psh[cc][n],Ssh[cc][n] for cc<c itself (identical order -> bit-exact vs the serial
// version). The independent LDS loads get hoisted; the fold is ~27 register FMAs done
// in parallel by all threads instead of 16 threads working while 27 waves idle.
__global__ __launch_bounds__(448) void scan_kernel(const u16* __restrict__ xzt,
                                                   const float* __restrict__ dbl,
                                                   const float* __restrict__ cw,
                                                   const float* __restrict__ cb,
                                                   const float* __restrict__ dtW,
                                                   const float* __restrict__ dtB,
                                                   const float* __restrict__ Alog,
                                                   const float* __restrict__ Dp,
                                                   u16* __restrict__ yt,
                                                   float* __restrict__ dblz) {
  int bd = blockIdx.x;          // b*DI + d
  int d  = bd % DI;
  int b  = bd / DI;
  int tid = threadIdx.x;
  int n = tid & 15, c = tid >> 4;   // c in [0,28)

  __shared__ float dtsh[L_];
  __shared__ float zsh[L_];
  __shared__ float xcsh[L_];
  __shared__ float Psh[NC][DS], Ssh[NC][DS];
  __shared__ float hC[L_][17];   // pad 17 -> conflict-free column access

  // zero slice of next dbl buffer (29 floats per block)
  {
    int i0 = blockIdx.x * 29 + tid;
    if (tid < 29 && i0 < T_ * 56) dblz[i0] = 0.f;
  }

  // cooperative: conv row (recompute), dt projection + softplus, silu(z) — one pass
  const float* wr = dtW + (size_t)d * DTR;   // block-uniform -> scalar loads
  float bias = dtB[d];
  float w0 = cw[d * 3 + 0], w1 = cw[d * 3 + 1], w2 = cw[d * 3 + 2], cbd = cb[d];
  const u16* xrow = xzt + (size_t)d * T_ + b * L_;
  const u16* zrow = xzt + (size_t)(DI + d) * T_ + b * L_;
  if (tid < L_) {
    int l = tid;
    const float4* dr4 = (const float4*)(dbl + (size_t)(b * L_ + l) * 56);
    float s = bias;
#pragma unroll
    for (int j = 0; j < 6; ++j) {
      float4 dv = dr4[j];
      s += dv.x * wr[j * 4 + 0] + dv.y * wr[j * 4 + 1]
         + dv.z * wr[j * 4 + 2] + dv.w * wr[j * 4 + 3];
    }
    dtsh[l] = (s > 20.f) ? s : log1pf(__expf(s));
    float zv = bf2f(zrow[l]);
    zsh[l] = zv / (1.f + __expf(-zv));
    float a = cbd + w2 * bf2f(xrow[l]);
    if (l >= 1) a += w1 * bf2f(xrow[l - 1]);
    if (l >= 2) a += w0 * bf2f(xrow[l - 2]);
    xcsh[l] = a / (1.f + __expf(-a));
  }
  float A  = -__expf(Alog[(size_t)d * DS + n]);
  float Dd = Dp[d];
  __syncthreads();

  int tb = b * L_ + c * CL;
  const float* Bp = dbl + (size_t)tb * 56 + DTR + n;
  const float* Cp = Bp + DS;

  float dA[CL], dBu[CL];
  {
    float P = 1.f, S = 0.f;
#pragma unroll
    for (int l = 0; l < CL; ++l) {
      float dtv = dtsh[c * CL + l];
      float xcv = xcsh[c * CL + l];
      float Bv  = Bp[l * 56];
      float e = __expf(dtv * A);
      float u = dtv * xcv * Bv;
      dA[l] = e; dBu[l] = u;
      P *= e;
      S = e * S + u;
    }
    Psh[c][n] = P; Ssh[c][n] = S;
  }
  __syncthreads();

  // redundant per-thread prefix fold over chunks cc < c (bit-exact same order as
  // the former 16-thread serial combine); loads are independent -> hoisted.
  float hh = 0.f;
#pragma unroll
  for (int cc = 0; cc < NC - 1; ++cc) {
    float ph = Psh[cc][n], sh = Ssh[cc][n];
    hh = (cc < c) ? (ph * hh + sh) : hh;
  }

  {
#pragma unroll
    for (int l = 0; l < CL; ++l) {
      hh = dA[l] * hh + dBu[l];
      hC[c * CL + l][n] = hh * Cp[l * 56];
    }
  }
  __syncthreads();
  if (tid < L_) {   // thread l: reduce over n, gate, coalesced y store
    int l = tid;
    float p = 0.f;
#pragma unroll
    for (int k = 0; k < DS; ++k) p += hC[l][k];
    yt[(size_t)d * T_ + b * L_ + l] = f2bf((p + Dd * xcsh[l]) * zsh[l]);
  }
}

extern "C" void kernel_launch(void* const* d_in, const int* in_sizes, int n_in,
                              void* d_out, int out_size, void* d_ws, size_t ws_size,
                              hipStream_t stream) {
  const float* z      = (const float*)d_in[0];
  const float* x      = (const float*)d_in[1];
  const float* patchW = (const float*)d_in[2];
  const float* patchB = (const float*)d_in[3];
  const float* pos    = (const float*)d_in[4];
  const float* normW  = (const float*)d_in[5];
  const float* normB  = (const float*)d_in[6];
  const float* inW    = (const float*)d_in[7];
  const float* convW  = (const float*)d_in[8];
  const float* convB  = (const float*)d_in[9];
  const float* xprojW = (const float*)d_in[10];
  const float* dtW    = (const float*)d_in[11];
  const float* dtB    = (const float*)d_in[12];
  const float* Alog   = (const float*)d_in[13];
  const float* Dpar   = (const float*)d_in[14];
  const float* outW   = (const float*)d_in[15];
  const float* fnW    = (const float*)d_in[16];
  const float* fnB    = (const float*)d_in[17];
  float* out = (float*)d_out;

  char* base = (char*)d_ws; size_t off = 0;
  auto alloc = [&](size_t bytes) {
    void* p = base + off; off = (off + bytes + 255) & ~(size_t)255; return p;
  };
  float* h    = (float*)alloc((size_t)T_ * DM * 4);
  u16*   xzt  = (u16*)  alloc((size_t)2 * DI * T_ * 2);       // [1536][T] bf16
  float* dbl  = (float*)alloc((size_t)2 * T_ * 56 * 4);       // double-buffered
  u16*   yt   = (u16*)  alloc((size_t)DI * T_ * 2);           // [DI][T] bf16
  u16*   imcolF=(u16*)  alloc((size_t)100 * 96 * 128 * 2);    // A-frag, 100 token-panels
  u16*   pwB  = (u16*)  alloc((size_t)DM * 768 * 2);          // frag layout
  u16*   inWb = (u16*)  alloc((size_t)DEPTH_ * 2 * DI * DM * 2);  // frag layout
  u16*   xpWb = (u16*)  alloc((size_t)DEPTH_ * 64 * DI * 2);  // frag layout, padded 56->64
  u16*   outWb= (u16*)  alloc((size_t)DEPTH_ * DM * DI * 2);  // frag layout

  // one-shot: all weights fp32 -> bf16 fragment layout; zero dbl buffers
  repack_kernel<<<dim3((RQ_TOT + 255) / 256), 256, 0, stream>>>(
      patchW, pwB, inW, inWb, xprojW, xpWb, outW, outWb, dbl);

  // patch embed: im2col (frag) + GEMM with fused bias+pos
  imcol_kernel<<<dim3(T_ * 768 / 256), 256, 0, stream>>>(z, x, imcolF);
  gemm_patch<<<dim3((T_ + 63) / 64, DM / 64), 256, 0, stream>>>(
      imcolF, pwB, patchB, pos, h);

  const int TG = (T_ + 63) / 64;  // 25
  for (int ly = 0; ly < DEPTH_; ++ly) {
    int p = ly & 1;
    float* dblc = dbl + (size_t)p * T_ * 56;
    float* dbln = dbl + (size_t)(p ^ 1) * T_ * 56;
    gemm_ln<<<dim3((2 * DI) / 64, TG), 256, 0, stream>>>(
        h, normW + (size_t)ly * DM, normB + (size_t)ly * DM,
        inWb + (size_t)ly * 2 * DI * DM, xzt);
    xproj_conv<<<dim3(TG, 1, DI / XKC), 256, 0, stream>>>(
        xzt, convW + (size_t)ly * DI * 3, convB + (size_t)ly * DI,
        xpWb + (size_t)ly * 64 * DI, dblc);
    scan_kernel<<<dim3(B_ * DI), 448, 0, stream>>>(
        xzt, dblc, convW + (size_t)ly * DI * 3, convB + (size_t)ly * DI,
        dtW + (size_t)ly * DI * DTR, dtB + (size_t)ly * DI,
        Alog + (size_t)ly * DI * DS, Dpar + (size_t)ly * DI, yt, dbln);
    gemm_out<<<dim3(TG, DM / 64, 2), 256, 0, stream>>>(
        yt, outWb + (size_t)ly * DM * DI, h);
  }

  ln_kernel<<<dim3(T_), dim3(DM), 0, stream>>>(h, fnW, fnB, out);
}

// Round 11
// 2020.008 us; speedup vs baseline: 1.2111x; 1.0292x over previous
//
#include <hip/hip_runtime.h>

typedef unsigned short u16;
typedef unsigned int   u32;

#define B_     4
#define L_     392
#define T_     1568   // B_*L_
#define DM     384
#define DI     768
#define DS     16
#define DTR    24
#define DEPTH_ 24
#define NPATCH 196
#define NC     28    // scan chunks
#define CL     14    // chunk length (NC*CL == L_)

// xproj_conv: K-split 8 -> 96 d's per block; LDS row pitch 104 (208B = 13*16B)
#define XKC    96
#define XPAD   104
// gemm_out: K-split 2 -> 384 d's per block; LDS row pitch 392 u16 (784B = 49*16B)
#define OKC    384
#define OPAD   392

typedef __bf16 bf16x8 __attribute__((ext_vector_type(8)));
typedef float  f32x4  __attribute__((ext_vector_type(4)));
typedef u16    u16x4  __attribute__((ext_vector_type(4)));
typedef u16    u16x8  __attribute__((ext_vector_type(8)));

__device__ __forceinline__ u16 f2bf(float f) {
  union { float f; u32 u; } v; v.f = f;
  return (u16)((v.u + 0x7fffu + ((v.u >> 16) & 1u)) >> 16);  // RNE
}
__device__ __forceinline__ float bf2f(u16 h) {
  union { u32 u; float f; } v; v.u = (u32)h << 16; return v.f;
}
// fast sigmoid-multiply: x * sigmoid(x), v_rcp_f32 (~1 ulp) instead of precise div
__device__ __forceinline__ float fsilu(float x) {
  return x * __builtin_amdgcn_rcpf(1.f + __expf(-x));
}

// ---------------- one-shot repack: fp32 -> bf16 fragment layout, DST-coalesced ----------------
// Fragment layout per matrix [R rows][K]: dst[ly][p=row/16][kb=k/8][r=row%16][e=k%8].
// Thread i owns dst u16 range [i*8, i*8+8) -> one 16B coalesced store; source side is
// two float4 loads (lanes l and l+16 share a 64B line).
#define RQ0 36864      // patchW: R=384  KB=96  L=1
#define RQ1 1769472    // inW:    R=1536 KB=48  L=24
#define RQ2 147456     // xpW:    Rp=64  KB=96  L=24 (rows 56..63 zero)
#define RQ3 884736     // outW:   R=384  KB=96  L=24
#define RQ4 43904      // dbl zero fill, float4 units
#define RQ_TOT (RQ0+RQ1+RQ2+RQ3+RQ4)

__global__ __launch_bounds__(256) void repack_kernel(
    const float* __restrict__ patchW, u16* __restrict__ pwB,
    const float* __restrict__ inW,    u16* __restrict__ inWb,
    const float* __restrict__ xpW,    u16* __restrict__ xpWb,
    const float* __restrict__ outW,   u16* __restrict__ outWb,
    float* __restrict__ dblz) {
  int i = blockIdx.x * 256 + threadIdx.x;
  const float* sp = nullptr; u16* dp = nullptr;
  if (i < RQ0) {                      // patchW
    int r = i & 15, kb = (i >> 4) % 96, p = i / (16 * 96);
    sp = patchW + (size_t)(p * 16 + r) * 768 + kb * 8;
    dp = pwB + (size_t)i * 8;
  } else { i -= RQ0;
  if (i < RQ1) {                      // inW
    const int per = 1536 * 48;
    int ly = i / per, rem = i - ly * per;
    int r = rem & 15, kb = (rem >> 4) % 48, p = rem / (16 * 48);
    sp = inW + (size_t)ly * 1536 * 384 + (size_t)(p * 16 + r) * 384 + kb * 8;
    dp = inWb + (size_t)i * 8;
  } else { i -= RQ1;
  if (i < RQ2) {                      // xpW (padded rows -> zeros)
    const int per = 64 * 96;
    int ly = i / per, rem = i - ly * per;
    int r = rem & 15, kb = (rem >> 4) % 96, p = rem / (16 * 96);
    int row = p * 16 + r;
    dp = xpWb + (size_t)i * 8;
    if (row < 56) {
      sp = xpW + (size_t)ly * 56 * 768 + (size_t)row * 768 + kb * 8;
    } else {
      u16x8 zz = {0,0,0,0,0,0,0,0};
      *(u16x8*)dp = zz;
      return;
    }
  } else { i -= RQ2;
  if (i < RQ3) {                      // outW
    const int per = 384 * 96;
    int ly = i / per, rem = i - ly * per;
    int r = rem & 15, kb = (rem >> 4) % 96, p = rem / (16 * 96);
    sp = outW + (size_t)ly * 384 * 768 + (size_t)(p * 16 + r) * 768 + kb * 8;
    dp = outWb + (size_t)i * 8;
  } else { i -= RQ3;
  if (i < RQ4) {                      // zero both dbl halves
    ((float4*)dblz)[i] = make_float4(0.f, 0.f, 0.f, 0.f);
  }
  return; } } } }
  float4 a = *(const float4*)sp;
  float4 b = *(const float4*)(sp + 4);
  u16x8 r8;
  r8[0] = f2bf(a.x); r8[1] = f2bf(a.y); r8[2] = f2bf(a.z); r8[3] = f2bf(a.w);
  r8[4] = f2bf(b.x); r8[5] = f2bf(b.y); r8[6] = f2bf(b.z); r8[7] = f2bf(b.w);
  *(u16x8*)dp = r8;
}

// ---------------- im2col for patch embed, emitting A-side fragment layout ----------------
__global__ __launch_bounds__(256) void imcol_kernel(const float* __restrict__ z,
                                                    const float* __restrict__ x,
                                                    u16* __restrict__ out) {
  int idx = blockIdx.x * 256 + threadIdx.x;        // t*768 + k
  int t = idx / 768, k = idx - t * 768;
  int b = t / L_, l = t - b * L_;
  const float* img = (l < NPATCH) ? z : x;
  int p  = (l < NPATCH) ? l : l - NPATCH;
  int py = p / 14, px = p - py * 14;
  int ic = k >> 8, rem = k & 255, i = rem >> 4, j = rem & 15;
  float v = img[((size_t)b * 3 + ic) * 50176 + (size_t)(py * 16 + i) * 224 + (px * 16 + j)];
  size_t o = ((size_t)(t >> 4) * 96 + (k >> 3)) * 128 + (size_t)(t & 15) * 8 + (k & 7);
  out[o] = f2bf(v);
}

// ---------------- patch embed GEMM: both operands fragment-native, no LDS ----------------
// h[t][n] = imcolF(t,:) . pwB(n,:) + patch_b[n] + pos[1 + (t%L)%NPATCH][n]. grid (25, 6).
__global__ __launch_bounds__(256) void gemm_patch(const u16* __restrict__ Af,
                                                  const u16* __restrict__ Wf,
                                                  const float* __restrict__ pb,
                                                  const float* __restrict__ pos,
                                                  float* __restrict__ h) {
  int wave = threadIdx.x >> 6, lane = threadIdx.x & 63;
  int r = lane & 15, quad = lane >> 4;
  int t0 = blockIdx.x * 64;
  int p  = blockIdx.y * 4 + wave;
  const u16* wp  = Wf + ((size_t)p * 96 + quad) * 128 + (size_t)r * 8;
  const u16* ap0 = Af + ((size_t)(t0 >> 4) * 96 + quad) * 128 + (size_t)r * 8;

  f32x4 acc[4] = {f32x4{0,0,0,0}, f32x4{0,0,0,0}, f32x4{0,0,0,0}, f32x4{0,0,0,0}};
#pragma unroll
  for (int k0 = 0; k0 < 768; k0 += 32) {
    bf16x8 bfrag = *(const bf16x8*)(wp + (size_t)(k0 >> 3) * 128);
#pragma unroll
    for (int mi = 0; mi < 4; ++mi) {
      bf16x8 afrag = *(const bf16x8*)(ap0 + ((size_t)mi * 96 + (k0 >> 3)) * 128);
      acc[mi] = __builtin_amdgcn_mfma_f32_16x16x32_bf16(afrag, bfrag, acc[mi], 0, 0, 0);
    }
  }
  int ccol = blockIdx.y * 64 + wave * 16 + r;
  float pbv = pb[ccol];
#pragma unroll
  for (int mi = 0; mi < 4; ++mi) {
#pragma unroll
    for (int rr = 0; rr < 4; ++rr) {
      int crow = t0 + mi * 16 + quad * 4 + rr;
      if (crow < T_) {
        int pp = (crow % L_) % NPATCH;
        h[(size_t)crow * DM + ccol] = acc[mi][rr] + pbv + pos[(size_t)(1 + pp) * DM + ccol];
      }
    }
  }
}

// ---------------- fused LayerNorm + in_proj GEMM (coalesced, frag weights) ----------------
__global__ __launch_bounds__(256) void gemm_ln(const float* __restrict__ h,
                                               const float* __restrict__ lw,
                                               const float* __restrict__ lb,
                                               const u16* __restrict__ W3,
                                               u16* __restrict__ xzt) {
  __shared__ u16 atile[64][392];
  int tid = threadIdx.x;
  int w = tid >> 6, l = tid & 63;
  int tok0 = blockIdx.y * 64;

  const int cA = 4 * l;
  const int cB = 256 + 4 * l;
  float4 wA = *(const float4*)(lw + cA);
  float4 bA = *(const float4*)(lb + cA);
  float4 wB = make_float4(0.f, 0.f, 0.f, 0.f), bB = wB;
  if (l < 32) { wB = *(const float4*)(lw + cB); bB = *(const float4*)(lb + cB); }

#pragma unroll 4
  for (int tt = 0; tt < 16; ++tt) {
    int t = w * 16 + tt;
    int tg = tok0 + t; if (tg > T_ - 1) tg = T_ - 1;
    const float* hrow = h + (size_t)tg * DM;
    float4 a = *(const float4*)(hrow + cA);
    float4 b2 = make_float4(0.f, 0.f, 0.f, 0.f);
    if (l < 32) b2 = *(const float4*)(hrow + cB);
    float s  = a.x + a.y + a.z + a.w + b2.x + b2.y + b2.z + b2.w;
    float s2 = a.x * a.x + a.y * a.y + a.z * a.z + a.w * a.w
             + b2.x * b2.x + b2.y * b2.y + b2.z * b2.z + b2.w * b2.w;
#pragma unroll
    for (int o = 32; o; o >>= 1) { s += __shfl_xor(s, o); s2 += __shfl_xor(s2, o); }
    float mu = s * (1.f / DM);
    float rs = rsqrtf(s2 * (1.f / DM) - mu * mu + 1e-5f);
    u16x4 r4;
    r4.x = f2bf((a.x - mu) * rs * wA.x + bA.x);
    r4.y = f2bf((a.y - mu) * rs * wA.y + bA.y);
    r4.z = f2bf((a.z - mu) * rs * wA.z + bA.z);
    r4.w = f2bf((a.w - mu) * rs * wA.w + bA.w);
    *(u16x4*)&atile[t][cA] = r4;
    if (l < 32) {
      u16x4 r4b;
      r4b.x = f2bf((b2.x - mu) * rs * wB.x + bB.x);
      r4b.y = f2bf((b2.y - mu) * rs * wB.y + bB.y);
      r4b.z = f2bf((b2.z - mu) * rs * wB.z + bB.z);
      r4b.w = f2bf((b2.w - mu) * rs * wB.w + bB.w);
      *(u16x4*)&atile[t][cB] = r4b;
    }
  }
  __syncthreads();

  int r = l & 15, u = l >> 4;
  int pbase = blockIdx.x * 4;
  const u16* wp = W3 + ((size_t)pbase * 48 + (size_t)u) * 128 + (size_t)r * 8;
  const u16* lp = &atile[w * 16 + r][u * 8];

  f32x4 acc[4] = {f32x4{0,0,0,0}, f32x4{0,0,0,0}, f32x4{0,0,0,0}, f32x4{0,0,0,0}};
#pragma unroll
  for (int k0 = 0; k0 < DM; k0 += 32) {
    bf16x8 bfrag = *(const bf16x8*)(lp + k0);
#pragma unroll
    for (int mi = 0; mi < 4; ++mi) {
      bf16x8 afrag = *(const bf16x8*)(wp + ((size_t)mi * 48 + (k0 >> 3)) * 128);
      acc[mi] = __builtin_amdgcn_mfma_f32_16x16x32_bf16(afrag, bfrag, acc[mi], 0, 0, 0);
    }
  }
  int ccol = tok0 + w * 16 + r;
  if (ccol < T_) {
#pragma unroll
    for (int mi = 0; mi < 4; ++mi) {
#pragma unroll
      for (int rr2 = 0; rr2 < 4; ++rr2) {
        int crow = pbase * 16 + mi * 16 + u * 4 + rr2;
        xzt[(size_t)crow * T_ + ccol] = f2bf(acc[mi][rr2]);
      }
    }
  }
}

// ---------------- fused conv3+SiLU + x_proj GEMM (frag weights, fast silu) ----------------
// dbl[T,56] += conv(xzt)·xpW^T over d-slice. grid (25, 1, 8), atomic epilogue.
__global__ __launch_bounds__(256) void xproj_conv(const u16* __restrict__ xzt,
                                                  const float* __restrict__ cw,
                                                  const float* __restrict__ cb,
                                                  const u16* __restrict__ Wx3,
                                                  float* __restrict__ dbl) {
  __shared__ u16 tile[64][XPAD];
  int t0 = blockIdx.x * 64;
  int kbeg = blockIdx.z * XKC;
  int tid = threadIdx.x;
  int tl = tid & 63, rq = tid >> 6;
  int t = t0 + tl;
  int tc = (t < T_) ? t : T_ - 1;
  int l = tc % L_;
  for (int kkb = rq * 2; kkb < XKC; kkb += 8) {
    u32 pack = 0;
#pragma unroll
    for (int ss = 0; ss < 2; ++ss) {
      int d = kbeg + kkb + ss;
      const u16* row = xzt + (size_t)d * T_ + tc;
      float acc = cb[d] + cw[d * 3 + 2] * bf2f(row[0]);
      if (l >= 1) acc += cw[d * 3 + 1] * bf2f(row[-1]);
      if (l >= 2) acc += cw[d * 3 + 0] * bf2f(row[-2]);
      pack |= (u32)f2bf(fsilu(acc)) << (16 * ss);
    }
    *(u32*)&tile[tl][kkb] = pack;
  }
  __syncthreads();

  int wave = tid >> 6, lane = tid & 63;
  int r = lane & 15, quad = lane >> 4;
  int wcol = wave * 16 + r;
  const u16* wp = Wx3 + ((size_t)wave * 96 + (kbeg >> 3) + quad) * 128 + (size_t)r * 8;

  f32x4 acc4[4] = {f32x4{0,0,0,0}, f32x4{0,0,0,0}, f32x4{0,0,0,0}, f32x4{0,0,0,0}};
#pragma unroll
  for (int k0 = 0; k0 < XKC; k0 += 32) {
    bf16x8 bfrag = *(const bf16x8*)(wp + (size_t)(k0 >> 3) * 128);
#pragma unroll
    for (int mi = 0; mi < 4; ++mi) {
      bf16x8 afrag = *(const bf16x8*)&tile[mi * 16 + r][k0 + quad * 8];
      acc4[mi] = __builtin_amdgcn_mfma_f32_16x16x32_bf16(afrag, bfrag, acc4[mi], 0, 0, 0);
    }
  }
  if (wcol < 56) {
#pragma unroll
    for (int mi = 0; mi < 4; ++mi) {
#pragma unroll
      for (int rr = 0; rr < 4; ++rr) {
        int crow = t0 + mi * 16 + quad * 4 + rr;
        if (crow < T_) atomicAdd(&dbl[(size_t)crow * 56 + wcol], acc4[mi][rr]);
      }
    }
  }
}

// ---------------- fused transpose + out_proj GEMM (frag weights, K-split 2) ----------------
// h[T,384] += y^T·outW^T over d-slice. grid (25, 6, 2), atomic epilogue.
__global__ __launch_bounds__(256) void gemm_out(const u16* __restrict__ yt,
                                                const u16* __restrict__ Wo3,
                                                float* __restrict__ h) {
  __shared__ u16 tile[64][OPAD];
  int t0 = blockIdx.x * 64;
  int kbeg = blockIdx.z * OKC;
  int tid = threadIdx.x;
  {
    int tl2 = tid & 31, rq = tid >> 5;   // 8 rows per pass
    for (int kk = rq; kk < OKC; kk += 8) {
      int d = kbeg + kk;
      u32 v = *(const u32*)(yt + (size_t)d * T_ + t0 + tl2 * 2);
      tile[tl2 * 2][kk]     = (u16)v;
      tile[tl2 * 2 + 1][kk] = (u16)(v >> 16);
    }
  }
  __syncthreads();

  int wave = tid >> 6, lane = tid & 63;
  int r = lane & 15, quad = lane >> 4;
  int p = blockIdx.y * 4 + wave;
  const u16* wp = Wo3 + ((size_t)p * 96 + (kbeg >> 3) + quad) * 128 + (size_t)r * 8;

  f32x4 acc[4] = {f32x4{0,0,0,0}, f32x4{0,0,0,0}, f32x4{0,0,0,0}, f32x4{0,0,0,0}};
#pragma unroll
  for (int k0 = 0; k0 < OKC; k0 += 32) {
    bf16x8 bfrag = *(const bf16x8*)(wp + (size_t)(k0 >> 3) * 128);
#pragma unroll
    for (int mi = 0; mi < 4; ++mi) {
      bf16x8 afrag = *(const bf16x8*)&tile[mi * 16 + r][k0 + quad * 8];
      acc[mi] = __builtin_amdgcn_mfma_f32_16x16x32_bf16(afrag, bfrag, acc[mi], 0, 0, 0);
    }
  }
  int ccol = blockIdx.y * 64 + wave * 16 + r;
#pragma unroll
  for (int mi = 0; mi < 4; ++mi) {
#pragma unroll
    for (int rr = 0; rr < 4; ++rr) {
      int crow = t0 + mi * 16 + quad * 4 + rr;
      if (crow < T_) atomicAdd(&h[(size_t)crow * DM + ccol], acc[mi][rr]);
    }
  }
}

// ---------------- LayerNorm over DM per token (final only) ----------------
__global__ __launch_bounds__(384) void ln_kernel(const float* __restrict__ x,
                                                 const float* __restrict__ w,
                                                 const float* __restrict__ b,
                                                 float* __restrict__ out_f) {
  int t = blockIdx.x;
  int i = threadIdx.x;
  float v = x[(size_t)t * DM + i];
  float s = v, s2 = v * v;
#pragma unroll
  for (int o = 32; o; o >>= 1) { s += __shfl_xor(s, o); s2 += __shfl_xor(s2, o); }
  __shared__ float ls[6], ls2[6];
  int wv = i >> 6;
  if ((i & 63) == 0) { ls[wv] = s; ls2[wv] = s2; }
  __syncthreads();
  float ts = 0.f, ts2 = 0.f;
#pragma unroll
  for (int j = 0; j < 6; ++j) { ts += ls[j]; ts2 += ls2[j]; }
  float mu  = ts * (1.f / DM);
  float var = ts2 * (1.f / DM) - mu * mu;
  float rs  = rsqrtf(var + 1e-5f);
  out_f[(size_t)t * DM + i] = (v - mu) * rs * w[i] + b[i];
}

// ---------------- chunked selective scan v12: round-6 structure + fast transcendentals ----------------
// 3072 blocks, vectorized dt-dot, hC transpose, 16-thread serial combine (best measured).
// softplus: __logf(1+e) instead of branchy log1pf; silu: v_rcp_f32 instead of precise div.
__global__ __launch_bounds__(448) void scan_kernel(const u16* __restrict__ xzt,
                                                   const float* __restrict__ dbl,
                                                   const float* __restrict__ cw,
                                                   const float* __restrict__ cb,
                                                   const float* __restrict__ dtW,
                                                   const float* __restrict__ dtB,
                                                   const float* __restrict__ Alog,
                                                   const float* __restrict__ Dp,
                                                   u16* __restrict__ yt,
                                                   float* __restrict__ dblz) {
  int bd = blockIdx.x;          // b*DI + d
  int d  = bd % DI;
  int b  = bd / DI;
  int tid = threadIdx.x;
  int n = tid & 15, c = tid >> 4;   // c in [0,28)

  __shared__ float dtsh[L_];
  __shared__ float zsh[L_];
  __shared__ float xcsh[L_];
  __shared__ float Psh[NC][DS], Ssh[NC][DS], Hsh[NC][DS];
  __shared__ float hC[L_][17];   // pad 17 -> conflict-free column access

  // zero slice of next dbl buffer (29 floats per block)
  {
    int i0 = blockIdx.x * 29 + tid;
    if (tid < 29 && i0 < T_ * 56) dblz[i0] = 0.f;
  }

  // cooperative: conv row (recompute), dt projection + softplus, silu(z) — one pass
  const float* wr = dtW + (size_t)d * DTR;   // block-uniform -> scalar loads
  float bias = dtB[d];
  float w0 = cw[d * 3 + 0], w1 = cw[d * 3 + 1], w2 = cw[d * 3 + 2], cbd = cb[d];
  const u16* xrow = xzt + (size_t)d * T_ + b * L_;
  const u16* zrow = xzt + (size_t)(DI + d) * T_ + b * L_;
  if (tid < L_) {
    int l = tid;
    const float4* dr4 = (const float4*)(dbl + (size_t)(b * L_ + l) * 56);
    float s = bias;
#pragma unroll
    for (int j = 0; j < 6; ++j) {
      float4 dv = dr4[j];
      s += dv.x * wr[j * 4 + 0] + dv.y * wr[j * 4 + 1]
         + dv.z * wr[j * 4 + 2] + dv.w * wr[j * 4 + 3];
    }
    dtsh[l] = (s > 20.f) ? s : __logf(1.f + __expf(s));
    zsh[l] = fsilu(bf2f(zrow[l]));
    float a = cbd + w2 * bf2f(xrow[l]);
    if (l >= 1) a += w1 * bf2f(xrow[l - 1]);
    if (l >= 2) a += w0 * bf2f(xrow[l - 2]);
    xcsh[l] = fsilu(a);
  }
  float A  = -__expf(Alog[(size_t)d * DS + n]);
  float Dd = Dp[d];
  __syncthreads();

  int tb = b * L_ + c * CL;
  const float* Bp = dbl + (size_t)tb * 56 + DTR + n;
  const float* Cp = Bp + DS;

  float dA[CL], dBu[CL];
  {
    float P = 1.f, S = 0.f;
#pragma unroll
    for (int l = 0; l < CL; ++l) {
      float dtv = dtsh[c * CL + l];
      float xcv = xcsh[c * CL + l];
      float Bv  = Bp[l * 56];
      float e = __expf(dtv * A);
      float u = dtv * xcv * Bv;
      dA[l] = e; dBu[l] = u;
      P *= e;
      S = e * S + u;
    }
    Psh[c][n] = P; Ssh[c][n] = S;
  }
  __syncthreads();
  if (tid < DS) {   // thread n: serial combine over 28 chunks
    float hh = 0.f;
#pragma unroll
    for (int cc = 0; cc < NC; ++cc) {
      Hsh[cc][tid] = hh;
      hh = Psh[cc][tid] * hh + Ssh[cc][tid];
    }
  }
  __syncthreads();
  {
    float hh = Hsh[c][n];
#pragma unroll
    for (int l = 0; l < CL; ++l) {
      hh = dA[l] * hh + dBu[l];
      hC[c * CL + l][n] = hh * Cp[l * 56];
    }
  }
  __syncthreads();
  if (tid < L_) {   // thread l: reduce over n, gate, coalesced y store
    int l = tid;
    float p = 0.f;
#pragma unroll
    for (int k = 0; k < DS; ++k) p += hC[l][k];
    yt[(size_t)d * T_ + b * L_ + l] = f2bf((p + Dd * xcsh[l]) * zsh[l]);
  }
}

extern "C" void kernel_launch(void* const* d_in, const int* in_sizes, int n_in,
                              void* d_out, int out_size, void* d_ws, size_t ws_size,
                              hipStream_t stream) {
  const float* z      = (const float*)d_in[0];
  const float* x      = (const float*)d_in[1];
  const float* patchW = (const float*)d_in[2];
  const float* patchB = (const float*)d_in[3];
  const float* pos    = (const float*)d_in[4];
  const float* normW  = (const float*)d_in[5];
  const float* normB  = (const float*)d_in[6];
  const float* inW    = (const float*)d_in[7];
  const float* convW  = (const float*)d_in[8];
  const float* convB  = (const float*)d_in[9];
  const float* xprojW = (const float*)d_in[10];
  const float* dtW    = (const float*)d_in[11];
  const float* dtB    = (const float*)d_in[12];
  const float* Alog   = (const float*)d_in[13];
  const float* Dpar   = (const float*)d_in[14];
  const float* outW   = (const float*)d_in[15];
  const float* fnW    = (const float*)d_in[16];
  const float* fnB    = (const float*)d_in[17];
  float* out = (float*)d_out;

  char* base = (char*)d_ws; size_t off = 0;
  auto alloc = [&](size_t bytes) {
    void* p = base + off; off = (off + bytes + 255) & ~(size_t)255; return p;
  };
  float* h    = (float*)alloc((size_t)T_ * DM * 4);
  u16*   xzt  = (u16*)  alloc((size_t)2 * DI * T_ * 2);       // [1536][T] bf16
  float* dbl  = (float*)alloc((size_t)2 * T_ * 56 * 4);       // double-buffered
  u16*   yt   = (u16*)  alloc((size_t)DI * T_ * 2);           // [DI][T] bf16
  u16*   imcolF=(u16*)  alloc((size_t)100 * 96 * 128 * 2);    // A-frag, 100 token-panels
  u16*   pwB  = (u16*)  alloc((size_t)DM * 768 * 2);          // frag layout
  u16*   inWb = (u16*)  alloc((size_t)DEPTH_ * 2 * DI * DM * 2);  // frag layout
  u16*   xpWb = (u16*)  alloc((size_t)DEPTH_ * 64 * DI * 2);  // frag layout, padded 56->64
  u16*   outWb= (u16*)  alloc((size_t)DEPTH_ * DM * DI * 2);  // frag layout

  // one-shot: all weights fp32 -> bf16 fragment layout; zero dbl buffers
  repack_kernel<<<dim3((RQ_TOT + 255) / 256), 256, 0, stream>>>(
      patchW, pwB, inW, inWb, xprojW, xpWb, outW, outWb, dbl);

  // patch embed: im2col (frag) + GEMM with fused bias+pos
  imcol_kernel<<<dim3(T_ * 768 / 256), 256, 0, stream>>>(z, x, imcolF);
  gemm_patch<<<dim3((T_ + 63) / 64, DM / 64), 256, 0, stream>>>(
      imcolF, pwB, patchB, pos, h);

  const int TG = (T_ + 63) / 64;  // 25
  for (int ly = 0; ly < DEPTH_; ++ly) {
    int p = ly & 1;
    float* dblc = dbl + (size_t)p * T_ * 56;
    float* dbln = dbl + (size_t)(p ^ 1) * T_ * 56;
    gemm_ln<<<dim3((2 * DI) / 64, TG), 256, 0, stream>>>(
        h, normW + (size_t)ly * DM, normB + (size_t)ly * DM,
        inWb + (size_t)ly * 2 * DI * DM, xzt);
    xproj_conv<<<dim3(TG, 1, DI / XKC), 256, 0, stream>>>(
        xzt, convW + (size_t)ly * DI * 3, convB + (size_t)ly * DI,
        xpWb + (size_t)ly * 64 * DI, dblc);
    scan_kernel<<<dim3(B_ * DI), 448, 0, stream>>>(
        xzt, dblc, convW + (size_t)ly * DI * 3, convB + (size_t)ly * DI,
        dtW + (size_t)ly * DI * DTR, dtB + (size_t)ly * DI,
        Alog + (size_t)ly * DI * DS, Dpar + (size_t)ly * DI, yt, dbln);
    gemm_out<<<dim3(TG, DM / 64, 2), 256, 0, stream>>>(
        yt, outWb + (size_t)ly * DM * DI, h);
  }

  ln_kernel<<<dim3(T_), dim3(DM), 0, stream>>>(h, fnW, fnB, out);
}